// Round 5
// baseline (389.025 us; speedup 1.0000x reference)
//
#include <hip/hip_runtime.h>
#include <hip/hip_bf16.h>
#include <math.h>

// ---------------------------------------------------------------------------
// UpdateAttn: decoder block = QKV proj -> MHA (no mask) -> Wo + res + LN1
//             -> Wff + res + LN2 -> 2*out + pos_emb(batch)
// S=2048 B=2 D=1024 H=16 DH=64.  All GEMMs bf16 MFMA; residual/LN in f32.
// R4: attn occupancy fix -- 16 q-rows/wave, 1024 blocks (4/CU, 16 waves/CU),
//     no block barriers.  Keeps: XCD-grouped L2-resident K/V, permuted-K
//     in-register P fragment, defer-max, 1-deep register prefetch.
// ---------------------------------------------------------------------------

typedef __bf16 bf16x8 __attribute__((ext_vector_type(8)));
typedef float f32x4  __attribute__((ext_vector_type(4)));

typedef const __attribute__((address_space(1))) unsigned int as1_uint;
typedef __attribute__((address_space(3))) unsigned int as3_uint;

constexpr int S_SEQ = 2048;
constexpr int DH    = 64;

#define WS_MB (1ull << 20)

__device__ __forceinline__ void gload16(void* lds, const void* g) {
  __builtin_amdgcn_global_load_lds((as1_uint*)g, (as3_uint*)lds, 16, 0, 0);
}

// -------------------------- f32 -> bf16 convert ----------------------------
__global__ void cvt_f32_bf16(const float* __restrict__ in,
                             __hip_bfloat16* __restrict__ out, int n4) {
  int idx = blockIdx.x * blockDim.x + threadIdx.x;
  if (idx >= n4) return;
  float4 v = ((const float4*)in)[idx];
  __hip_bfloat16 tmp[4];
  tmp[0] = __float2bfloat16(v.x);
  tmp[1] = __float2bfloat16(v.y);
  tmp[2] = __float2bfloat16(v.z);
  tmp[3] = __float2bfloat16(v.w);
  *(uint2*)(out + (size_t)idx * 4) = *(uint2*)tmp;
}

// ------------------------------ pos table ----------------------------------
__global__ void pe_kernel(float* __restrict__ pe) {
  int k = blockIdx.x * blockDim.x + threadIdx.x;
  if (k >= 512) return;
  float freq = expf(-(2.0f * (float)k / 1024.0f) * logf(10000.0f));
  pe[2 * k]          = 0.0f;          // pos 0: sin(0)
  pe[2 * k + 1]      = 1.0f;          // pos 0: cos(0)
  pe[1024 + 2 * k]     = sinf(freq);  // pos 1
  pe[1024 + 2 * k + 1] = cosf(freq);
}

// ------------------------------ GEMM (B^T) ---------------------------------
template <int MODE>
__global__ __launch_bounds__(256)
void gemm_bt(const __hip_bfloat16* __restrict__ A,
             const __hip_bfloat16* __restrict__ Bw,
             float* __restrict__ C,
             __hip_bfloat16* __restrict__ Qb,
             __hip_bfloat16* __restrict__ Kb,
             __hip_bfloat16* __restrict__ VTb,
             int Ndim, int Kdim) {
  constexpr int BK = 64;
  __shared__ __hip_bfloat16 sA[128 * BK];
  __shared__ __hip_bfloat16 sB[128 * BK];
  const int t = threadIdx.x, w = t >> 6, l = t & 63;
  const int bm = blockIdx.y * 128, bn = blockIdx.x * 128;
  const int m0 = (w >> 1) * 64, n0 = (w & 1) * 64;
  const int lrow = l >> 3, lcol = l & 7;
  const int ll = l & 15, lg = l >> 4;

  f32x4 acc[4][4] = {};

  for (int kt = 0; kt < Kdim; kt += BK) {
    __syncthreads();
#pragma unroll
    for (int r = 0; r < 4; ++r) {
      const int chunk = r * 4 + w;
      const int row = chunk * 8 + lrow;
      gload16((char*)sA + chunk * 1024 + l * 16,
              A + (size_t)(bm + row) * Kdim + kt + lcol * 8);
      gload16((char*)sB + chunk * 1024 + l * 16,
              Bw + (size_t)(bn + row) * Kdim + kt + lcol * 8);
    }
    __syncthreads();
#pragma unroll
    for (int ks = 0; ks < 2; ++ks) {
      bf16x8 a[4], b[4];
#pragma unroll
      for (int mi = 0; mi < 4; ++mi)
        a[mi] = *(const bf16x8*)((const char*)sA +
                 (m0 + mi * 16 + ll) * 128 + ks * 64 + lg * 16);
#pragma unroll
      for (int ni = 0; ni < 4; ++ni)
        b[ni] = *(const bf16x8*)((const char*)sB +
                 (n0 + ni * 16 + ll) * 128 + ks * 64 + lg * 16);
#pragma unroll
      for (int mi = 0; mi < 4; ++mi)
#pragma unroll
        for (int ni = 0; ni < 4; ++ni)
          acc[mi][ni] = __builtin_amdgcn_mfma_f32_16x16x32_bf16(
              a[mi], b[ni], acc[mi][ni], 0, 0, 0);
    }
  }

#pragma unroll
  for (int mi = 0; mi < 4; ++mi)
#pragma unroll
    for (int ni = 0; ni < 4; ++ni)
#pragma unroll
      for (int r = 0; r < 4; ++r) {
        const int gm = bm + m0 + mi * 16 + lg * 4 + r;
        const int gn = bn + n0 + ni * 16 + ll;
        const float v = acc[mi][ni][r];
        if (MODE == 0) {
          C[(size_t)gm * Ndim + gn] = v;
        } else {
          const int i = gm >> 1, bb = gm & 1;
          const __hip_bfloat16 hv = __float2bfloat16(v);
          if (gn < 1024) {
            const int h = gn >> 6, dh = gn & 63;
            Qb[(((size_t)(bb * 16 + h)) * 2048 + i) * 64 + dh] = hv;
          } else if (gn < 2048) {
            const int e = gn - 1024, h = e >> 6, dh = e & 63;
            Kb[(((size_t)(bb * 16 + h)) * 2048 + i) * 64 + dh] = hv;
          } else {
            const int e = gn - 2048, h = e >> 6, dh = e & 63;
            VTb[(((size_t)(bb * 16 + h)) * 64 + dh) * 2048 + i] = hv;
          }
        }
      }
}

// ----------------------------- flash attention ------------------------------
// Single pass, online softmax with defer-max; permuted-K rows give the PV
// A-fragment in-register.  1024 blocks, XCD-grouped: xcd = bid&7 owns a fixed
// group of 4 bh (2 MB K/V, L2-resident).  Wave owns 16 q rows; 4 blocks/CU.

#define LOADKV(kk, vv, jj)                                                    \
  {                                                                           \
    const __hip_bfloat16* Kj = K + (size_t)(jj) * 64;                         \
    kk[0] = *(const bf16x8*)(Kj + pr0 * 64 + lg * 8);                         \
    kk[1] = *(const bf16x8*)(Kj + pr0 * 64 + 32 + lg * 8);                    \
    kk[2] = *(const bf16x8*)(Kj + (pr0 + 4) * 64 + lg * 8);                   \
    kk[3] = *(const bf16x8*)(Kj + (pr0 + 4) * 64 + 32 + lg * 8);              \
    _Pragma("unroll")                                                         \
    for (int df = 0; df < 4; ++df)                                            \
      vv[df] = *(const bf16x8*)(VT + (size_t)(df * 16 + ll) * S_SEQ + (jj) +  \
                                lg * 8);                                      \
  }

#define COMPUTE(kk, vv)                                                       \
  {                                                                           \
    f32x4 z = {0.f, 0.f, 0.f, 0.f};                                           \
    f32x4 s0, s1;                                                             \
    s0 = __builtin_amdgcn_mfma_f32_16x16x32_bf16(kk[0], qf0, z, 0, 0, 0);     \
    s0 = __builtin_amdgcn_mfma_f32_16x16x32_bf16(kk[1], qf1, s0, 0, 0, 0);    \
    s1 = __builtin_amdgcn_mfma_f32_16x16x32_bf16(kk[2], qf0, z, 0, 0, 0);     \
    s1 = __builtin_amdgcn_mfma_f32_16x16x32_bf16(kk[3], qf1, s1, 0, 0, 0);    \
    float a = fmaxf(fmaxf(s0[0], s0[1]), fmaxf(s0[2], s0[3]));                \
    float c = fmaxf(fmaxf(s1[0], s1[1]), fmaxf(s1[2], s1[3]));                \
    float pm = fmaxf(a, c) * C1;                                              \
    pm = fmaxf(pm, __shfl_xor(pm, 16));                                       \
    pm = fmaxf(pm, __shfl_xor(pm, 32));                                       \
    if (__any(pm > mm + THR2)) {                                              \
      const float nm = fmaxf(mm, pm);                                         \
      const float al = exp2f(mm - nm);                                        \
      mm = nm;                                                                \
      lsum *= al;                                                             \
      float aR[4];                                                            \
      _Pragma("unroll")                                                       \
      for (int r = 0; r < 4; ++r) aR[r] = __shfl(al, 4 * lg + r);             \
      _Pragma("unroll")                                                       \
      for (int df = 0; df < 4; ++df)                                          \
        _Pragma("unroll")                                                     \
        for (int r = 0; r < 4; ++r) oacc[df][r] *= aR[r];                     \
    }                                                                         \
    float p[8];                                                               \
    _Pragma("unroll")                                                         \
    for (int r = 0; r < 4; ++r) {                                             \
      p[r]     = exp2f(fmaf(s0[r], C1, -mm));                                 \
      p[4 + r] = exp2f(fmaf(s1[r], C1, -mm));                                 \
    }                                                                         \
    lsum += ((p[0] + p[1]) + (p[2] + p[3])) +                                 \
            ((p[4] + p[5]) + (p[6] + p[7]));                                  \
    union { __hip_bfloat16 hx[8]; bf16x8 v; } pk;                             \
    _Pragma("unroll")                                                         \
    for (int j = 0; j < 8; ++j) pk.hx[j] = __float2bfloat16(p[j]);            \
    _Pragma("unroll")                                                         \
    for (int df = 0; df < 4; ++df)                                            \
      oacc[df] = __builtin_amdgcn_mfma_f32_16x16x32_bf16(                     \
          pk.v, vv[df], oacc[df], 0, 0, 0);                                   \
  }

__global__ __launch_bounds__(256)
void attn_kernel(const __hip_bfloat16* __restrict__ Qb,
                 const __hip_bfloat16* __restrict__ Kb,
                 const __hip_bfloat16* __restrict__ VTb,
                 __hip_bfloat16* __restrict__ vec) {
  const int t = threadIdx.x, w = t >> 6, l = t & 63;
  // 1024 blocks; xcd = bid&7 (round-robin) owns bh group of 4; qt = 0..31.
  const int bid = blockIdx.x;
  const int slot = bid >> 3;
  const int bh = (bid & 7) * 4 + (slot & 3);
  const int qt = slot >> 2;                       // 0..31
  const int b = bh >> 4, h = bh & 15;
  const __hip_bfloat16* Q  = Qb + (size_t)bh * S_SEQ * DH;
  const __hip_bfloat16* K  = Kb + (size_t)bh * S_SEQ * DH;
  const __hip_bfloat16* VT = VTb + (size_t)bh * DH * S_SEQ;
  const int ll = l & 15, lg = l >> 4;
  constexpr float C1   = 0.125f * 1.44269504088896f;  // scale * log2(e)
  constexpr float THR2 = 11.5416f;                    // 8 nats in exp2 domain

  const int qbase = qt * 64 + w * 16;
  const bf16x8 qf0 = *(const bf16x8*)(Q + (size_t)(qbase + ll) * 64 + lg * 8);
  const bf16x8 qf1 = *(const bf16x8*)(Q + (size_t)(qbase + ll) * 64 + 32 + lg * 8);
  const int pr0 = 8 * (ll >> 2) + (ll & 3);   // permuted K row for MFMA-0

  float mm   = -1e30f;
  float lsum = 0.f;
  f32x4 oacc[4] = {};

  bf16x8 ka[4], va[4], kb[4], vb[4];
  LOADKV(ka, va, 0);

  for (int j0 = 0; j0 < S_SEQ; j0 += 64) {
    LOADKV(kb, vb, j0 + 32);                  // prefetch tile j0+32
    COMPUTE(ka, va);
    {
      const int jn = (j0 + 64 < S_SEQ) ? j0 + 64 : 0;   // benign tail load
      LOADKV(ka, va, jn);                     // prefetch tile j0+64
    }
    COMPUTE(kb, vb);
  }

  // epilogue: reduce row-sums, normalize, write
  float ls = lsum;
  ls += __shfl_xor(ls, 16);
  ls += __shfl_xor(ls, 32);
  const float inv = 1.0f / ls;            // for q = ll
  float invR[4];
#pragma unroll
  for (int r = 0; r < 4; ++r) invR[r] = __shfl(inv, 4 * lg + r);
#pragma unroll
  for (int df = 0; df < 4; ++df)
#pragma unroll
    for (int r = 0; r < 4; ++r) {
      const int row = qbase + 4 * lg + r;
      const int e = h * 64 + df * 16 + ll;
      vec[((size_t)row * 2 + b) * 1024 + e] =
          __float2bfloat16(oacc[df][r] * invR[r]);
    }
}

// --------------------- residual add + LayerNorm (fused) ---------------------
__global__ __launch_bounds__(256)
void add_ln_kernel(const float* __restrict__ X, const float* __restrict__ Yadd,
                   const float* __restrict__ g, const float* __restrict__ bb,
                   float* __restrict__ out_f32,
                   __hip_bfloat16* __restrict__ out_b16) {
  const int row = blockIdx.x, t = threadIdx.x;
  const float4 x4 = *(const float4*)(X + (size_t)row * 1024 + t * 4);
  const float4 a4 = *(const float4*)(Yadd + (size_t)row * 1024 + t * 4);
  float v[4] = {x4.x + a4.x, x4.y + a4.y, x4.z + a4.z, x4.w + a4.w};
  float s = v[0] + v[1] + v[2] + v[3];
  float s2 = v[0] * v[0] + v[1] * v[1] + v[2] * v[2] + v[3] * v[3];
#pragma unroll
  for (int off = 1; off < 64; off <<= 1) {
    s += __shfl_xor(s, off);
    s2 += __shfl_xor(s2, off);
  }
  __shared__ float rs[4], rs2[4];
  if ((t & 63) == 0) { rs[t >> 6] = s; rs2[t >> 6] = s2; }
  __syncthreads();
  const float tot = rs[0] + rs[1] + rs[2] + rs[3];
  const float tot2 = rs2[0] + rs2[1] + rs2[2] + rs2[3];
  const float mu = tot * (1.0f / 1024.0f);
  const float var = tot2 * (1.0f / 1024.0f) - mu * mu;
  const float rstd = rsqrtf(var + 1e-5f);
  const float4 g4 = *(const float4*)(g + t * 4);
  const float4 b4 = *(const float4*)(bb + t * 4);
  float y[4];
  y[0] = (v[0] - mu) * rstd * g4.x + b4.x;
  y[1] = (v[1] - mu) * rstd * g4.y + b4.y;
  y[2] = (v[2] - mu) * rstd * g4.z + b4.z;
  y[3] = (v[3] - mu) * rstd * g4.w + b4.w;
  *(float4*)(out_f32 + (size_t)row * 1024 + t * 4) =
      make_float4(y[0], y[1], y[2], y[3]);
  __hip_bfloat16 tmp[4] = {__float2bfloat16(y[0]), __float2bfloat16(y[1]),
                           __float2bfloat16(y[2]), __float2bfloat16(y[3])};
  *(uint2*)(out_b16 + (size_t)row * 1024 + t * 4) = *(uint2*)tmp;
}

// ---------------- residual add + LayerNorm + 2*y + pe (final) ---------------
__global__ __launch_bounds__(256)
void final_kernel(const float* __restrict__ X, const float* __restrict__ Yadd,
                  const float* __restrict__ g, const float* __restrict__ bb,
                  const float* __restrict__ pe, float* __restrict__ out) {
  const int row = blockIdx.x, t = threadIdx.x;
  const float4 x4 = *(const float4*)(X + (size_t)row * 1024 + t * 4);
  const float4 a4 = *(const float4*)(Yadd + (size_t)row * 1024 + t * 4);
  float v[4] = {x4.x + a4.x, x4.y + a4.y, x4.z + a4.z, x4.w + a4.w};
  float s = v[0] + v[1] + v[2] + v[3];
  float s2 = v[0] * v[0] + v[1] * v[1] + v[2] * v[2] + v[3] * v[3];
#pragma unroll
  for (int off = 1; off < 64; off <<= 1) {
    s += __shfl_xor(s, off);
    s2 += __shfl_xor(s2, off);
  }
  __shared__ float rs[4], rs2[4];
  if ((t & 63) == 0) { rs[t >> 6] = s; rs2[t >> 6] = s2; }
  __syncthreads();
  const float tot = rs[0] + rs[1] + rs[2] + rs[3];
  const float tot2 = rs2[0] + rs2[1] + rs2[2] + rs2[3];
  const float mu = tot * (1.0f / 1024.0f);
  const float var = tot2 * (1.0f / 1024.0f) - mu * mu;
  const float rstd = rsqrtf(var + 1e-5f);
  const float4 g4 = *(const float4*)(g + t * 4);
  const float4 b4 = *(const float4*)(bb + t * 4);
  const int bidx = row & 1;
  const float4 p4 = *(const float4*)(pe + bidx * 1024 + t * 4);
  float y[4];
  y[0] = 2.0f * ((v[0] - mu) * rstd * g4.x + b4.x) + p4.x;
  y[1] = 2.0f * ((v[1] - mu) * rstd * g4.y + b4.y) + p4.y;
  y[2] = 2.0f * ((v[2] - mu) * rstd * g4.z + b4.z) + p4.z;
  y[3] = 2.0f * ((v[3] - mu) * rstd * g4.w + b4.w) + p4.w;
  *(float4*)(out + (size_t)row * 1024 + t * 4) = make_float4(y[0], y[1], y[2], y[3]);
}

// ---------------------------------------------------------------------------
extern "C" void kernel_launch(void* const* d_in, const int* in_sizes, int n_in,
                              void* d_out, int out_size, void* d_ws,
                              size_t ws_size, hipStream_t stream) {
  const float* x   = (const float*)d_in[0];
  const float* Wq  = (const float*)d_in[1];
  const float* Wkv = (const float*)d_in[2];
  const float* Wo  = (const float*)d_in[3];
  const float* g1  = (const float*)d_in[4];
  const float* b1  = (const float*)d_in[5];
  const float* Wff = (const float*)d_in[6];
  const float* g2  = (const float*)d_in[7];
  const float* b2  = (const float*)d_in[8];

  char* ws = (char*)d_ws;
  __hip_bfloat16* Wqkv_b = (__hip_bfloat16*)(ws + 0);          // 6 MB
  __hip_bfloat16* Wo_b   = (__hip_bfloat16*)(ws + 6 * WS_MB);  // 2 MB
  __hip_bfloat16* Wff_b  = (__hip_bfloat16*)(ws + 8 * WS_MB);  // 2 MB
  __hip_bfloat16* Xb     = (__hip_bfloat16*)(ws + 10 * WS_MB); // 8 MB
  __hip_bfloat16* Qb     = (__hip_bfloat16*)(ws + 18 * WS_MB); // 8 MB
  __hip_bfloat16* Kb     = (__hip_bfloat16*)(ws + 26 * WS_MB); // 8 MB
  __hip_bfloat16* VTb    = (__hip_bfloat16*)(ws + 34 * WS_MB); // 8 MB
  __hip_bfloat16* vecb   = (__hip_bfloat16*)(ws + 42 * WS_MB); // 8 MB
  float* attn            = (float*)(ws + 18 * WS_MB);          // 16 MB (alias Q+K)
  float* out1            = (float*)(ws + 50 * WS_MB);          // 16 MB
  __hip_bfloat16* out1b  = (__hip_bfloat16*)(ws + 66 * WS_MB); // 8 MB
  float* ffb             = (float*)(ws + 34 * WS_MB);          // 16 MB (alias VT+vec)
  float* pe              = (float*)(ws + 74 * WS_MB);          // 8 KB

  cvt_f32_bf16<<<4096, 256, 0, stream>>>(x, Xb, 1048576);
  cvt_f32_bf16<<<1024, 256, 0, stream>>>(Wq, Wqkv_b, 262144);
  cvt_f32_bf16<<<2048, 256, 0, stream>>>(Wkv, Wqkv_b + 1024 * 1024, 524288);
  cvt_f32_bf16<<<1024, 256, 0, stream>>>(Wo, Wo_b, 262144);
  cvt_f32_bf16<<<1024, 256, 0, stream>>>(Wff, Wff_b, 262144);
  pe_kernel<<<1, 512, 0, stream>>>(pe);

  gemm_bt<1><<<dim3(24, 32), 256, 0, stream>>>(Xb, Wqkv_b, nullptr, Qb, Kb, VTb,
                                               3072, 1024);
  attn_kernel<<<dim3(1024), 256, 0, stream>>>(Qb, Kb, VTb, vecb);
  gemm_bt<0><<<dim3(8, 32), 256, 0, stream>>>(vecb, Wo_b, attn, nullptr, nullptr,
                                              nullptr, 1024, 1024);
  add_ln_kernel<<<4096, 256, 0, stream>>>(x, attn, g1, b1, out1, out1b);
  gemm_bt<0><<<dim3(8, 32), 256, 0, stream>>>(out1b, Wff_b, ffb, nullptr, nullptr,
                                              nullptr, 1024, 1024);
  final_kernel<<<4096, 256, 0, stream>>>(out1, ffb, g2, b2, pe, (float*)d_out);
}

// Round 6
// 277.628 us; speedup vs baseline: 1.4012x; 1.4012x over previous
//
#include <hip/hip_runtime.h>
#include <hip/hip_bf16.h>
#include <math.h>

// ---------------------------------------------------------------------------
// UpdateAttn: decoder block = QKV proj -> MHA (no mask) -> Wo + res + LN1
//             -> Wff + res + LN2 -> 2*out + pos_emb(batch)
// S=2048 B=2 D=1024 H=16 DH=64.  All GEMMs bf16 MFMA; residual/LN in f32.
// R5: attn VALU diet -- v_cvt_pk_bf16_f32 (1 instr per 2 cvts), raw v_exp_f32,
//     row-sum via ones-MFMA (C-layout, no epilogue shfl), shuffle-free
//     defer-max common path, 32 q-rows/wave, 2-deep register prefetch.
// ---------------------------------------------------------------------------

typedef __bf16 bf16x8 __attribute__((ext_vector_type(8)));
typedef float f32x4  __attribute__((ext_vector_type(4)));

typedef const __attribute__((address_space(1))) unsigned int as1_uint;
typedef __attribute__((address_space(3))) unsigned int as3_uint;

constexpr int S_SEQ = 2048;
constexpr int DH    = 64;

#define WS_MB (1ull << 20)

__device__ __forceinline__ void gload16(void* lds, const void* g) {
  __builtin_amdgcn_global_load_lds((as1_uint*)g, (as3_uint*)lds, 16, 0, 0);
}

__device__ __forceinline__ float fast_exp2(float x) {
  float r;
  asm volatile("v_exp_f32 %0, %1\n\ts_nop 1" : "=v"(r) : "v"(x));
  return r;
}
__device__ __forceinline__ unsigned cvt_pk_bf16(float lo, float hi) {
  unsigned r;
  asm("v_cvt_pk_bf16_f32 %0, %1, %2" : "=v"(r) : "v"(lo), "v"(hi));
  return r;
}

// -------------------------- f32 -> bf16 convert ----------------------------
__global__ void cvt_f32_bf16(const float* __restrict__ in,
                             __hip_bfloat16* __restrict__ out, int n4) {
  int idx = blockIdx.x * blockDim.x + threadIdx.x;
  if (idx >= n4) return;
  float4 v = ((const float4*)in)[idx];
  __hip_bfloat16 tmp[4];
  tmp[0] = __float2bfloat16(v.x);
  tmp[1] = __float2bfloat16(v.y);
  tmp[2] = __float2bfloat16(v.z);
  tmp[3] = __float2bfloat16(v.w);
  *(uint2*)(out + (size_t)idx * 4) = *(uint2*)tmp;
}

// ------------------------------ pos table ----------------------------------
__global__ void pe_kernel(float* __restrict__ pe) {
  int k = blockIdx.x * blockDim.x + threadIdx.x;
  if (k >= 512) return;
  float freq = expf(-(2.0f * (float)k / 1024.0f) * logf(10000.0f));
  pe[2 * k]          = 0.0f;          // pos 0: sin(0)
  pe[2 * k + 1]      = 1.0f;          // pos 0: cos(0)
  pe[1024 + 2 * k]     = sinf(freq);  // pos 1
  pe[1024 + 2 * k + 1] = cosf(freq);
}

// ------------------------------ GEMM (B^T) ---------------------------------
template <int MODE>
__global__ __launch_bounds__(256)
void gemm_bt(const __hip_bfloat16* __restrict__ A,
             const __hip_bfloat16* __restrict__ Bw,
             float* __restrict__ C,
             __hip_bfloat16* __restrict__ Qb,
             __hip_bfloat16* __restrict__ Kb,
             __hip_bfloat16* __restrict__ VTb,
             int Ndim, int Kdim) {
  constexpr int BK = 64;
  __shared__ __hip_bfloat16 sA[128 * BK];
  __shared__ __hip_bfloat16 sB[128 * BK];
  const int t = threadIdx.x, w = t >> 6, l = t & 63;
  const int bm = blockIdx.y * 128, bn = blockIdx.x * 128;
  const int m0 = (w >> 1) * 64, n0 = (w & 1) * 64;
  const int lrow = l >> 3, lcol = l & 7;
  const int ll = l & 15, lg = l >> 4;

  f32x4 acc[4][4] = {};

  for (int kt = 0; kt < Kdim; kt += BK) {
    __syncthreads();
#pragma unroll
    for (int r = 0; r < 4; ++r) {
      const int chunk = r * 4 + w;
      const int row = chunk * 8 + lrow;
      gload16((char*)sA + chunk * 1024 + l * 16,
              A + (size_t)(bm + row) * Kdim + kt + lcol * 8);
      gload16((char*)sB + chunk * 1024 + l * 16,
              Bw + (size_t)(bn + row) * Kdim + kt + lcol * 8);
    }
    __syncthreads();
#pragma unroll
    for (int ks = 0; ks < 2; ++ks) {
      bf16x8 a[4], b[4];
#pragma unroll
      for (int mi = 0; mi < 4; ++mi)
        a[mi] = *(const bf16x8*)((const char*)sA +
                 (m0 + mi * 16 + ll) * 128 + ks * 64 + lg * 16);
#pragma unroll
      for (int ni = 0; ni < 4; ++ni)
        b[ni] = *(const bf16x8*)((const char*)sB +
                 (n0 + ni * 16 + ll) * 128 + ks * 64 + lg * 16);
#pragma unroll
      for (int mi = 0; mi < 4; ++mi)
#pragma unroll
        for (int ni = 0; ni < 4; ++ni)
          acc[mi][ni] = __builtin_amdgcn_mfma_f32_16x16x32_bf16(
              a[mi], b[ni], acc[mi][ni], 0, 0, 0);
    }
  }

#pragma unroll
  for (int mi = 0; mi < 4; ++mi)
#pragma unroll
    for (int ni = 0; ni < 4; ++ni)
#pragma unroll
      for (int r = 0; r < 4; ++r) {
        const int gm = bm + m0 + mi * 16 + lg * 4 + r;
        const int gn = bn + n0 + ni * 16 + ll;
        const float v = acc[mi][ni][r];
        if (MODE == 0) {
          C[(size_t)gm * Ndim + gn] = v;
        } else {
          const int i = gm >> 1, bb = gm & 1;
          const __hip_bfloat16 hv = __float2bfloat16(v);
          if (gn < 1024) {
            const int h = gn >> 6, dh = gn & 63;
            Qb[(((size_t)(bb * 16 + h)) * 2048 + i) * 64 + dh] = hv;
          } else if (gn < 2048) {
            const int e = gn - 1024, h = e >> 6, dh = e & 63;
            Kb[(((size_t)(bb * 16 + h)) * 2048 + i) * 64 + dh] = hv;
          } else {
            const int e = gn - 2048, h = e >> 6, dh = e & 63;
            VTb[(((size_t)(bb * 16 + h)) * 64 + dh) * 2048 + i] = hv;
          }
        }
      }
}

// ----------------------------- flash attention ------------------------------
// Single pass, online softmax with defer-max; permuted-K rows give the PV
// A-fragment in-register.  512 blocks, XCD-grouped (bid&7 -> group of 4 bh,
// 2 MB K/V L2-resident).  Wave owns 32 q-rows (qi=0,1); 2-deep reg prefetch.
// Common path has ZERO cross-lane ops; row-sum accumulated by a ones-B MFMA
// directly in C-layout.

#define MFMA_B16 __builtin_amdgcn_mfma_f32_16x16x32_bf16

#define LOADKV(kk, vv, jj)                                                    \
  {                                                                           \
    const char* Kj = (const char*)K + (size_t)(jj) * 128 + koff;              \
    kk[0] = *(const bf16x8*)(Kj);                                             \
    kk[1] = *(const bf16x8*)(Kj + 64);                                        \
    kk[2] = *(const bf16x8*)(Kj + 512);                                       \
    kk[3] = *(const bf16x8*)(Kj + 576);                                       \
    const char* Vj = (const char*)VT + (size_t)(jj) * 2 + voff;               \
    vv[0] = *(const bf16x8*)(Vj);                                             \
    vv[1] = *(const bf16x8*)(Vj + 16 * 4096);                                 \
    vv[2] = *(const bf16x8*)(Vj + 32 * 4096);                                 \
    vv[3] = *(const bf16x8*)(Vj + 48 * 4096);                                 \
  }

#define COMPUTE(kk, vv)                                                       \
  {                                                                           \
    const f32x4 z = {0.f, 0.f, 0.f, 0.f};                                     \
    f32x4 s0[2], s1[2];                                                       \
    s0[0] = MFMA_B16(kk[0], qf[0][0], z, 0, 0, 0);                            \
    s0[0] = MFMA_B16(kk[1], qf[0][1], s0[0], 0, 0, 0);                        \
    s1[0] = MFMA_B16(kk[2], qf[0][0], z, 0, 0, 0);                            \
    s1[0] = MFMA_B16(kk[3], qf[0][1], s1[0], 0, 0, 0);                        \
    s0[1] = MFMA_B16(kk[0], qf[1][0], z, 0, 0, 0);                            \
    s0[1] = MFMA_B16(kk[1], qf[1][1], s0[1], 0, 0, 0);                        \
    s1[1] = MFMA_B16(kk[2], qf[1][0], z, 0, 0, 0);                            \
    s1[1] = MFMA_B16(kk[3], qf[1][1], s1[1], 0, 0, 0);                        \
    float plm[2];                                                             \
    _Pragma("unroll")                                                         \
    for (int qi = 0; qi < 2; ++qi) {                                          \
      float a = fmaxf(fmaxf(s0[qi][0], s0[qi][1]),                            \
                      fmaxf(s0[qi][2], s0[qi][3]));                           \
      float c = fmaxf(fmaxf(s1[qi][0], s1[qi][1]),                            \
                      fmaxf(s1[qi][2], s1[qi][3]));                           \
      plm[qi] = fmaxf(a, c) * C1;                                             \
    }                                                                         \
    if (__any((plm[0] > mm[0] + THR2) || (plm[1] > mm[1] + THR2))) {          \
      _Pragma("unroll")                                                       \
      for (int qi = 0; qi < 2; ++qi) {                                        \
        float pm = plm[qi];                                                   \
        pm = fmaxf(pm, __shfl_xor(pm, 16));                                   \
        pm = fmaxf(pm, __shfl_xor(pm, 32));                                   \
        const float nm = fmaxf(mm[qi], pm);                                   \
        const float al = fast_exp2(mm[qi] - nm);                              \
        mm[qi] = nm;                                                          \
        float aR[4];                                                          \
        _Pragma("unroll")                                                     \
        for (int r = 0; r < 4; ++r) aR[r] = __shfl(al, 4 * lg + r);           \
        _Pragma("unroll")                                                     \
        for (int df = 0; df < 4; ++df)                                        \
          _Pragma("unroll")                                                   \
          for (int r = 0; r < 4; ++r) oacc[qi][df][r] *= aR[r];               \
        _Pragma("unroll")                                                     \
        for (int r = 0; r < 4; ++r) oaccS[qi][r] *= aR[r];                    \
      }                                                                       \
    }                                                                         \
    _Pragma("unroll")                                                         \
    for (int qi = 0; qi < 2; ++qi) {                                          \
      float p[8];                                                             \
      _Pragma("unroll")                                                       \
      for (int r = 0; r < 4; ++r) {                                           \
        p[r]     = fast_exp2(fmaf(s0[qi][r], C1, -mm[qi]));                   \
        p[4 + r] = fast_exp2(fmaf(s1[qi][r], C1, -mm[qi]));                   \
      }                                                                       \
      union { unsigned u[4]; bf16x8 v; } pk;                                  \
      pk.u[0] = cvt_pk_bf16(p[0], p[1]);                                      \
      pk.u[1] = cvt_pk_bf16(p[2], p[3]);                                      \
      pk.u[2] = cvt_pk_bf16(p[4], p[5]);                                      \
      pk.u[3] = cvt_pk_bf16(p[6], p[7]);                                      \
      _Pragma("unroll")                                                       \
      for (int df = 0; df < 4; ++df)                                          \
        oacc[qi][df] = MFMA_B16(pk.v, vv[df], oacc[qi][df], 0, 0, 0);         \
      oaccS[qi] = MFMA_B16(pk.v, onesv.v, oaccS[qi], 0, 0, 0);                \
    }                                                                         \
  }

__global__ __launch_bounds__(256)
void attn_kernel(const __hip_bfloat16* __restrict__ Qb,
                 const __hip_bfloat16* __restrict__ Kb,
                 const __hip_bfloat16* __restrict__ VTb,
                 __hip_bfloat16* __restrict__ vec) {
  const int t = threadIdx.x, w = t >> 6, l = t & 63;
  // 512 blocks; xcd = bid&7 owns a fixed group of 4 bh; qt = 0..15.
  const int bid = blockIdx.x;
  const int slot = bid >> 3;
  const int bh = (bid & 7) * 4 + (slot & 3);
  const int qt = slot >> 2;                       // 0..15
  const int b = bh >> 4, h = bh & 15;
  const __hip_bfloat16* Q  = Qb + (size_t)bh * S_SEQ * DH;
  const __hip_bfloat16* K  = Kb + (size_t)bh * S_SEQ * DH;
  const __hip_bfloat16* VT = VTb + (size_t)bh * DH * S_SEQ;
  const int ll = l & 15, lg = l >> 4;
  constexpr float C1   = 0.125f * 1.44269504088896f;  // scale * log2(e)
  constexpr float THR2 = 11.5416f;                    // 8 nats in exp2 domain

  const int qbase = qt * 128 + w * 32;
  bf16x8 qf[2][2];
#pragma unroll
  for (int qi = 0; qi < 2; ++qi) {
    qf[qi][0] = *(const bf16x8*)(Q + (size_t)(qbase + qi * 16 + ll) * 64 + lg * 8);
    qf[qi][1] = *(const bf16x8*)(Q + (size_t)(qbase + qi * 16 + ll) * 64 + 32 + lg * 8);
  }
  const int pr0 = 8 * (ll >> 2) + (ll & 3);       // permuted K row for MFMA-0
  const int koff = pr0 * 128 + lg * 16;           // lane byte offset into K tile
  const int voff = ll * 4096 + lg * 16;           // lane byte offset into V^T

  union { unsigned u[4]; bf16x8 v; } onesv;       // bf16 1.0 x8
  onesv.u[0] = 0x3F803F80u; onesv.u[1] = 0x3F803F80u;
  onesv.u[2] = 0x3F803F80u; onesv.u[3] = 0x3F803F80u;

  float mm[2] = {-1e30f, -1e30f};
  f32x4 oacc[2][4] = {};
  f32x4 oaccS[2] = {};                            // row-sums, C-layout

  bf16x8 kA[4], vA[4], kB[4], vB[4], kC[4], vC[4], kD[4], vD[4];
  LOADKV(kA, vA, 0);
  LOADKV(kB, vB, 32);

  for (int j0 = 0; j0 < S_SEQ; j0 += 128) {
    LOADKV(kC, vC, j0 + 64);
    LOADKV(kD, vD, j0 + 96);
    COMPUTE(kA, vA);
    COMPUTE(kB, vB);
    {
      const int jn = (j0 + 128 < S_SEQ) ? j0 + 128 : 0;  // benign tail wrap
      LOADKV(kA, vA, jn);
      LOADKV(kB, vB, jn + 32);
    }
    COMPUTE(kC, vC);
    COMPUTE(kD, vD);
  }

  // epilogue: inv row-sum is already per-lane in C-layout (no shuffles)
#pragma unroll
  for (int qi = 0; qi < 2; ++qi) {
    float invR[4];
#pragma unroll
    for (int r = 0; r < 4; ++r) invR[r] = 1.0f / oaccS[qi][r];
#pragma unroll
    for (int df = 0; df < 4; ++df)
#pragma unroll
      for (int r = 0; r < 4; ++r) {
        const int row = qbase + qi * 16 + 4 * lg + r;
        const int e = h * 64 + df * 16 + ll;
        vec[((size_t)row * 2 + b) * 1024 + e] =
            __float2bfloat16(oacc[qi][df][r] * invR[r]);
      }
  }
}

// --------------------- residual add + LayerNorm (fused) ---------------------
__global__ __launch_bounds__(256)
void add_ln_kernel(const float* __restrict__ X, const float* __restrict__ Yadd,
                   const float* __restrict__ g, const float* __restrict__ bb,
                   float* __restrict__ out_f32,
                   __hip_bfloat16* __restrict__ out_b16) {
  const int row = blockIdx.x, t = threadIdx.x;
  const float4 x4 = *(const float4*)(X + (size_t)row * 1024 + t * 4);
  const float4 a4 = *(const float4*)(Yadd + (size_t)row * 1024 + t * 4);
  float v[4] = {x4.x + a4.x, x4.y + a4.y, x4.z + a4.z, x4.w + a4.w};
  float s = v[0] + v[1] + v[2] + v[3];
  float s2 = v[0] * v[0] + v[1] * v[1] + v[2] * v[2] + v[3] * v[3];
#pragma unroll
  for (int off = 1; off < 64; off <<= 1) {
    s += __shfl_xor(s, off);
    s2 += __shfl_xor(s2, off);
  }
  __shared__ float rs[4], rs2[4];
  if ((t & 63) == 0) { rs[t >> 6] = s; rs2[t >> 6] = s2; }
  __syncthreads();
  const float tot = rs[0] + rs[1] + rs[2] + rs[3];
  const float tot2 = rs2[0] + rs2[1] + rs2[2] + rs2[3];
  const float mu = tot * (1.0f / 1024.0f);
  const float var = tot2 * (1.0f / 1024.0f) - mu * mu;
  const float rstd = rsqrtf(var + 1e-5f);
  const float4 g4 = *(const float4*)(g + t * 4);
  const float4 b4 = *(const float4*)(bb + t * 4);
  float y[4];
  y[0] = (v[0] - mu) * rstd * g4.x + b4.x;
  y[1] = (v[1] - mu) * rstd * g4.y + b4.y;
  y[2] = (v[2] - mu) * rstd * g4.z + b4.z;
  y[3] = (v[3] - mu) * rstd * g4.w + b4.w;
  *(float4*)(out_f32 + (size_t)row * 1024 + t * 4) =
      make_float4(y[0], y[1], y[2], y[3]);
  __hip_bfloat16 tmp[4] = {__float2bfloat16(y[0]), __float2bfloat16(y[1]),
                           __float2bfloat16(y[2]), __float2bfloat16(y[3])};
  *(uint2*)(out_b16 + (size_t)row * 1024 + t * 4) = *(uint2*)tmp;
}

// ---------------- residual add + LayerNorm + 2*y + pe (final) ---------------
__global__ __launch_bounds__(256)
void final_kernel(const float* __restrict__ X, const float* __restrict__ Yadd,
                  const float* __restrict__ g, const float* __restrict__ bb,
                  const float* __restrict__ pe, float* __restrict__ out) {
  const int row = blockIdx.x, t = threadIdx.x;
  const float4 x4 = *(const float4*)(X + (size_t)row * 1024 + t * 4);
  const float4 a4 = *(const float4*)(Yadd + (size_t)row * 1024 + t * 4);
  float v[4] = {x4.x + a4.x, x4.y + a4.y, x4.z + a4.z, x4.w + a4.w};
  float s = v[0] + v[1] + v[2] + v[3];
  float s2 = v[0] * v[0] + v[1] * v[1] + v[2] * v[2] + v[3] * v[3];
#pragma unroll
  for (int off = 1; off < 64; off <<= 1) {
    s += __shfl_xor(s, off);
    s2 += __shfl_xor(s2, off);
  }
  __shared__ float rs[4], rs2[4];
  if ((t & 63) == 0) { rs[t >> 6] = s; rs2[t >> 6] = s2; }
  __syncthreads();
  const float tot = rs[0] + rs[1] + rs[2] + rs[3];
  const float tot2 = rs2[0] + rs2[1] + rs2[2] + rs2[3];
  const float mu = tot * (1.0f / 1024.0f);
  const float var = tot2 * (1.0f / 1024.0f) - mu * mu;
  const float rstd = rsqrtf(var + 1e-5f);
  const float4 g4 = *(const float4*)(g + t * 4);
  const float4 b4 = *(const float4*)(bb + t * 4);
  const int bidx = row & 1;
  const float4 p4 = *(const float4*)(pe + bidx * 1024 + t * 4);
  float y[4];
  y[0] = 2.0f * ((v[0] - mu) * rstd * g4.x + b4.x) + p4.x;
  y[1] = 2.0f * ((v[1] - mu) * rstd * g4.y + b4.y) + p4.y;
  y[2] = 2.0f * ((v[2] - mu) * rstd * g4.z + b4.z) + p4.z;
  y[3] = 2.0f * ((v[3] - mu) * rstd * g4.w + b4.w) + p4.w;
  *(float4*)(out + (size_t)row * 1024 + t * 4) = make_float4(y[0], y[1], y[2], y[3]);
}

// ---------------------------------------------------------------------------
extern "C" void kernel_launch(void* const* d_in, const int* in_sizes, int n_in,
                              void* d_out, int out_size, void* d_ws,
                              size_t ws_size, hipStream_t stream) {
  const float* x   = (const float*)d_in[0];
  const float* Wq  = (const float*)d_in[1];
  const float* Wkv = (const float*)d_in[2];
  const float* Wo  = (const float*)d_in[3];
  const float* g1  = (const float*)d_in[4];
  const float* b1  = (const float*)d_in[5];
  const float* Wff = (const float*)d_in[6];
  const float* g2  = (const float*)d_in[7];
  const float* b2  = (const float*)d_in[8];

  char* ws = (char*)d_ws;
  __hip_bfloat16* Wqkv_b = (__hip_bfloat16*)(ws + 0);          // 6 MB
  __hip_bfloat16* Wo_b   = (__hip_bfloat16*)(ws + 6 * WS_MB);  // 2 MB
  __hip_bfloat16* Wff_b  = (__hip_bfloat16*)(ws + 8 * WS_MB);  // 2 MB
  __hip_bfloat16* Xb     = (__hip_bfloat16*)(ws + 10 * WS_MB); // 8 MB
  __hip_bfloat16* Qb     = (__hip_bfloat16*)(ws + 18 * WS_MB); // 8 MB
  __hip_bfloat16* Kb     = (__hip_bfloat16*)(ws + 26 * WS_MB); // 8 MB
  __hip_bfloat16* VTb    = (__hip_bfloat16*)(ws + 34 * WS_MB); // 8 MB
  __hip_bfloat16* vecb   = (__hip_bfloat16*)(ws + 42 * WS_MB); // 8 MB
  float* attn            = (float*)(ws + 18 * WS_MB);          // 16 MB (alias Q+K)
  float* out1            = (float*)(ws + 50 * WS_MB);          // 16 MB
  __hip_bfloat16* out1b  = (__hip_bfloat16*)(ws + 66 * WS_MB); // 8 MB
  float* ffb             = (float*)(ws + 34 * WS_MB);          // 16 MB (alias VT+vec)
  float* pe              = (float*)(ws + 74 * WS_MB);          // 8 KB

  cvt_f32_bf16<<<4096, 256, 0, stream>>>(x, Xb, 1048576);
  cvt_f32_bf16<<<1024, 256, 0, stream>>>(Wq, Wqkv_b, 262144);
  cvt_f32_bf16<<<2048, 256, 0, stream>>>(Wkv, Wqkv_b + 1024 * 1024, 524288);
  cvt_f32_bf16<<<1024, 256, 0, stream>>>(Wo, Wo_b, 262144);
  cvt_f32_bf16<<<1024, 256, 0, stream>>>(Wff, Wff_b, 262144);
  pe_kernel<<<1, 512, 0, stream>>>(pe);

  gemm_bt<1><<<dim3(24, 32), 256, 0, stream>>>(Xb, Wqkv_b, nullptr, Qb, Kb, VTb,
                                               3072, 1024);
  attn_kernel<<<dim3(512), 256, 0, stream>>>(Qb, Kb, VTb, vecb);
  gemm_bt<0><<<dim3(8, 32), 256, 0, stream>>>(vecb, Wo_b, attn, nullptr, nullptr,
                                              nullptr, 1024, 1024);
  add_ln_kernel<<<4096, 256, 0, stream>>>(x, attn, g1, b1, out1, out1b);
  gemm_bt<0><<<dim3(8, 32), 256, 0, stream>>>(out1b, Wff_b, ffb, nullptr, nullptr,
                                              nullptr, 1024, 1024);
  final_kernel<<<4096, 256, 0, stream>>>(out1, ffb, g2, b2, pe, (float*)d_out);
}

// Round 7
// 208.719 us; speedup vs baseline: 1.8639x; 1.3302x over previous
//
#include <hip/hip_runtime.h>
#include <hip/hip_bf16.h>
#include <math.h>

// ---------------------------------------------------------------------------
// UpdateAttn: decoder block = QKV proj -> MHA (no mask) -> Wo + res + LN1
//             -> Wff + res + LN2 -> 2*out + pos_emb(batch)
// S=2048 B=2 D=1024 H=16 DH=64.  All GEMMs bf16 MFMA; residual/LN in f32.
// R6: K/V scratch stored in MFMA-FRAGMENT-CONTIGUOUS layout (producer-side
//     permutation in the QKV epilogue scatter) -> every attn K/V load is a
//     fully-coalesced 1KB dwordx4 with immediate offset.  Attn loop keeps:
//     defer-max, in-register P, ones-MFMA row-sum, 2-deep prefetch.
// ---------------------------------------------------------------------------

typedef __bf16 bf16x8 __attribute__((ext_vector_type(8)));
typedef float f32x4  __attribute__((ext_vector_type(4)));

typedef const __attribute__((address_space(1))) unsigned int as1_uint;
typedef __attribute__((address_space(3))) unsigned int as3_uint;

constexpr int S_SEQ = 2048;
constexpr int DH    = 64;

#define WS_MB (1ull << 20)

__device__ __forceinline__ void gload16(void* lds, const void* g) {
  __builtin_amdgcn_global_load_lds((as1_uint*)g, (as3_uint*)lds, 16, 0, 0);
}

__device__ __forceinline__ float fast_exp2(float x) {
  float r;
  asm volatile("v_exp_f32 %0, %1\n\ts_nop 1" : "=v"(r) : "v"(x));
  return r;
}
__device__ __forceinline__ unsigned cvt_pk_bf16(float lo, float hi) {
  unsigned r;
  asm("v_cvt_pk_bf16_f32 %0, %1, %2" : "=v"(r) : "v"(lo), "v"(hi));
  return r;
}

// -------------------------- f32 -> bf16 convert ----------------------------
__global__ void cvt_f32_bf16(const float* __restrict__ in,
                             __hip_bfloat16* __restrict__ out, int n4) {
  int idx = blockIdx.x * blockDim.x + threadIdx.x;
  if (idx >= n4) return;
  float4 v = ((const float4*)in)[idx];
  __hip_bfloat16 tmp[4];
  tmp[0] = __float2bfloat16(v.x);
  tmp[1] = __float2bfloat16(v.y);
  tmp[2] = __float2bfloat16(v.z);
  tmp[3] = __float2bfloat16(v.w);
  *(uint2*)(out + (size_t)idx * 4) = *(uint2*)tmp;
}

// ------------------------------ pos table ----------------------------------
__global__ void pe_kernel(float* __restrict__ pe) {
  int k = blockIdx.x * blockDim.x + threadIdx.x;
  if (k >= 512) return;
  float freq = expf(-(2.0f * (float)k / 1024.0f) * logf(10000.0f));
  pe[2 * k]          = 0.0f;          // pos 0: sin(0)
  pe[2 * k + 1]      = 1.0f;          // pos 0: cos(0)
  pe[1024 + 2 * k]     = sinf(freq);  // pos 1
  pe[1024 + 2 * k + 1] = cosf(freq);
}

// ------------------------------ GEMM (B^T) ---------------------------------
// MODE 1 scatter targets:
//   Q : Qb[bh][i][dh]                       (row-major per head)
//   K : Kf[bh][tile][instr][lane][8]        (attn kk[instr] fragment order)
//   V : Vf[bh][tile][df][lane][8]           (attn vv[df] fragment order)
// where tile = i>>5, lane = lg*16+ll; K: row-in-tile r32 = 8*(ll>>2)+(ll&3)
// (+4 for instr>=2), dh = (instr&1)*32 + lg*8 + e;  V: kv = lg*8+e, dh = df*16+ll.
template <int MODE>
__global__ __launch_bounds__(256)
void gemm_bt(const __hip_bfloat16* __restrict__ A,
             const __hip_bfloat16* __restrict__ Bw,
             float* __restrict__ C,
             __hip_bfloat16* __restrict__ Qb,
             __hip_bfloat16* __restrict__ Kb,
             __hip_bfloat16* __restrict__ VTb,
             int Ndim, int Kdim) {
  constexpr int BK = 64;
  __shared__ __hip_bfloat16 sA[128 * BK];
  __shared__ __hip_bfloat16 sB[128 * BK];
  const int t = threadIdx.x, w = t >> 6, l = t & 63;
  const int bm = blockIdx.y * 128, bn = blockIdx.x * 128;
  const int m0 = (w >> 1) * 64, n0 = (w & 1) * 64;
  const int lrow = l >> 3, lcol = l & 7;
  const int ll = l & 15, lg = l >> 4;

  f32x4 acc[4][4] = {};

  for (int kt = 0; kt < Kdim; kt += BK) {
    __syncthreads();
#pragma unroll
    for (int r = 0; r < 4; ++r) {
      const int chunk = r * 4 + w;
      const int row = chunk * 8 + lrow;
      gload16((char*)sA + chunk * 1024 + l * 16,
              A + (size_t)(bm + row) * Kdim + kt + lcol * 8);
      gload16((char*)sB + chunk * 1024 + l * 16,
              Bw + (size_t)(bn + row) * Kdim + kt + lcol * 8);
    }
    __syncthreads();
#pragma unroll
    for (int ks = 0; ks < 2; ++ks) {
      bf16x8 a[4], b[4];
#pragma unroll
      for (int mi = 0; mi < 4; ++mi)
        a[mi] = *(const bf16x8*)((const char*)sA +
                 (m0 + mi * 16 + ll) * 128 + ks * 64 + lg * 16);
#pragma unroll
      for (int ni = 0; ni < 4; ++ni)
        b[ni] = *(const bf16x8*)((const char*)sB +
                 (n0 + ni * 16 + ll) * 128 + ks * 64 + lg * 16);
#pragma unroll
      for (int mi = 0; mi < 4; ++mi)
#pragma unroll
        for (int ni = 0; ni < 4; ++ni)
          acc[mi][ni] = __builtin_amdgcn_mfma_f32_16x16x32_bf16(
              a[mi], b[ni], acc[mi][ni], 0, 0, 0);
    }
  }

#pragma unroll
  for (int mi = 0; mi < 4; ++mi)
#pragma unroll
    for (int ni = 0; ni < 4; ++ni)
#pragma unroll
      for (int r = 0; r < 4; ++r) {
        const int gm = bm + m0 + mi * 16 + lg * 4 + r;
        const int gn = bn + n0 + ni * 16 + ll;
        const float v = acc[mi][ni][r];
        if (MODE == 0) {
          C[(size_t)gm * Ndim + gn] = v;
        } else {
          const int i = gm >> 1, bb = gm & 1;
          const __hip_bfloat16 hv = __float2bfloat16(v);
          if (gn < 1024) {
            const int h = gn >> 6, dh = gn & 63;
            Qb[(((size_t)(bb * 16 + h)) * 2048 + i) * 64 + dh] = hv;
          } else if (gn < 2048) {
            const int e = gn - 1024, h = e >> 6, dh = e & 63;
            const int bh2 = bb * 16 + h;
            const int tile = i >> 5, r32 = i & 31;
            const int a8 = r32 & 7, b8 = r32 >> 3;
            const int hi = dh >> 5, w32 = dh & 31;
            const int lg2 = w32 >> 3, be = w32 & 7;
            const int ll2 = b8 * 4 + (a8 & 3);
            const int instr = (a8 < 4 ? 0 : 2) + hi;
            const int lane = lg2 * 16 + ll2;
            Kb[(size_t)bh2 * 131072 + tile * 2048 + instr * 512 + lane * 8 + be] = hv;
          } else {
            const int e = gn - 2048, h = e >> 6, dh = e & 63;
            const int bh2 = bb * 16 + h;
            const int tile = i >> 5, r32 = i & 31;
            const int lg2 = r32 >> 3, e8 = r32 & 7;
            const int ll2 = dh & 15, df = dh >> 4;
            const int lane = lg2 * 16 + ll2;
            VTb[(size_t)bh2 * 131072 + tile * 2048 + df * 512 + lane * 8 + e8] = hv;
          }
        }
      }
}

// ----------------------------- flash attention ------------------------------
// Single pass, online softmax with defer-max; fragment-contiguous K/V loads
// (1 KB coalesced dwordx4, immediate offsets).  512 blocks, XCD-grouped
// (bid&7 -> group of 4 bh, 2 MB K/V L2-resident).  Wave owns 32 q-rows;
// 2-deep register prefetch; row-sum via ones-B MFMA in C-layout.

#define MFMA_B16 __builtin_amdgcn_mfma_f32_16x16x32_bf16

#define LOADKV(kk, vv, tb)                                                    \
  {                                                                           \
    const char* Kj = Kf + (tb);                                               \
    kk[0] = *(const bf16x8*)(Kj + l16);                                       \
    kk[1] = *(const bf16x8*)(Kj + 1024 + l16);                                \
    kk[2] = *(const bf16x8*)(Kj + 2048 + l16);                                \
    kk[3] = *(const bf16x8*)(Kj + 3072 + l16);                                \
    const char* Vj = Vf + (tb);                                               \
    vv[0] = *(const bf16x8*)(Vj + l16);                                       \
    vv[1] = *(const bf16x8*)(Vj + 1024 + l16);                                \
    vv[2] = *(const bf16x8*)(Vj + 2048 + l16);                                \
    vv[3] = *(const bf16x8*)(Vj + 3072 + l16);                                \
  }

#define COMPUTE(kk, vv)                                                       \
  {                                                                           \
    const f32x4 z = {0.f, 0.f, 0.f, 0.f};                                     \
    f32x4 s0[2], s1[2];                                                       \
    s0[0] = MFMA_B16(kk[0], qf[0][0], z, 0, 0, 0);                            \
    s0[0] = MFMA_B16(kk[1], qf[0][1], s0[0], 0, 0, 0);                        \
    s1[0] = MFMA_B16(kk[2], qf[0][0], z, 0, 0, 0);                            \
    s1[0] = MFMA_B16(kk[3], qf[0][1], s1[0], 0, 0, 0);                        \
    s0[1] = MFMA_B16(kk[0], qf[1][0], z, 0, 0, 0);                            \
    s0[1] = MFMA_B16(kk[1], qf[1][1], s0[1], 0, 0, 0);                        \
    s1[1] = MFMA_B16(kk[2], qf[1][0], z, 0, 0, 0);                            \
    s1[1] = MFMA_B16(kk[3], qf[1][1], s1[1], 0, 0, 0);                        \
    float plm[2];                                                             \
    _Pragma("unroll")                                                         \
    for (int qi = 0; qi < 2; ++qi) {                                          \
      float a = fmaxf(fmaxf(s0[qi][0], s0[qi][1]),                            \
                      fmaxf(s0[qi][2], s0[qi][3]));                           \
      float c = fmaxf(fmaxf(s1[qi][0], s1[qi][1]),                            \
                      fmaxf(s1[qi][2], s1[qi][3]));                           \
      plm[qi] = fmaxf(a, c) * C1;                                             \
    }                                                                         \
    if (__any((plm[0] > mm[0] + THR2) || (plm[1] > mm[1] + THR2))) {          \
      _Pragma("unroll")                                                       \
      for (int qi = 0; qi < 2; ++qi) {                                        \
        float pm = plm[qi];                                                   \
        pm = fmaxf(pm, __shfl_xor(pm, 16));                                   \
        pm = fmaxf(pm, __shfl_xor(pm, 32));                                   \
        const float nm = fmaxf(mm[qi], pm);                                   \
        const float al = fast_exp2(mm[qi] - nm);                              \
        mm[qi] = nm;                                                          \
        float aR[4];                                                          \
        _Pragma("unroll")                                                     \
        for (int r = 0; r < 4; ++r) aR[r] = __shfl(al, 4 * lg + r);           \
        _Pragma("unroll")                                                     \
        for (int df = 0; df < 4; ++df)                                        \
          _Pragma("unroll")                                                   \
          for (int r = 0; r < 4; ++r) oacc[qi][df][r] *= aR[r];               \
        _Pragma("unroll")                                                     \
        for (int r = 0; r < 4; ++r) oaccS[qi][r] *= aR[r];                    \
      }                                                                       \
    }                                                                         \
    _Pragma("unroll")                                                         \
    for (int qi = 0; qi < 2; ++qi) {                                          \
      float p[8];                                                             \
      _Pragma("unroll")                                                       \
      for (int r = 0; r < 4; ++r) {                                           \
        p[r]     = fast_exp2(fmaf(s0[qi][r], C1, -mm[qi]));                   \
        p[4 + r] = fast_exp2(fmaf(s1[qi][r], C1, -mm[qi]));                   \
      }                                                                       \
      union { unsigned u[4]; bf16x8 v; } pk;                                  \
      pk.u[0] = cvt_pk_bf16(p[0], p[1]);                                      \
      pk.u[1] = cvt_pk_bf16(p[2], p[3]);                                      \
      pk.u[2] = cvt_pk_bf16(p[4], p[5]);                                      \
      pk.u[3] = cvt_pk_bf16(p[6], p[7]);                                      \
      _Pragma("unroll")                                                       \
      for (int df = 0; df < 4; ++df)                                          \
        oacc[qi][df] = MFMA_B16(pk.v, vv[df], oacc[qi][df], 0, 0, 0);         \
      oaccS[qi] = MFMA_B16(pk.v, onesv.v, oaccS[qi], 0, 0, 0);                \
    }                                                                         \
  }

__global__ __launch_bounds__(256)
void attn_kernel(const __hip_bfloat16* __restrict__ Qb,
                 const __hip_bfloat16* __restrict__ Kb,
                 const __hip_bfloat16* __restrict__ VTb,
                 __hip_bfloat16* __restrict__ vec) {
  const int t = threadIdx.x, w = t >> 6, l = t & 63;
  // 512 blocks; xcd = bid&7 owns a fixed group of 4 bh; qt = 0..15.
  const int bid = blockIdx.x;
  const int slot = bid >> 3;
  const int bh = (bid & 7) * 4 + (slot & 3);
  const int qt = slot >> 2;                       // 0..15
  const int b = bh >> 4, h = bh & 15;
  const __hip_bfloat16* Q = Qb + (size_t)bh * S_SEQ * DH;
  const char* Kf = (const char*)Kb + (size_t)bh * 262144;   // 256 KB / bh
  const char* Vf = (const char*)VTb + (size_t)bh * 262144;
  const int ll = l & 15, lg = l >> 4;
  const int l16 = l * 16;
  constexpr float C1   = 0.125f * 1.44269504088896f;  // scale * log2(e)
  constexpr float THR2 = 11.5416f;                    // 8 nats in exp2 domain

  const int qbase = qt * 128 + w * 32;
  bf16x8 qf[2][2];
#pragma unroll
  for (int qi = 0; qi < 2; ++qi) {
    qf[qi][0] = *(const bf16x8*)(Q + (size_t)(qbase + qi * 16 + ll) * 64 + lg * 8);
    qf[qi][1] = *(const bf16x8*)(Q + (size_t)(qbase + qi * 16 + ll) * 64 + 32 + lg * 8);
  }

  union { unsigned u[4]; bf16x8 v; } onesv;       // bf16 1.0 x8
  onesv.u[0] = 0x3F803F80u; onesv.u[1] = 0x3F803F80u;
  onesv.u[2] = 0x3F803F80u; onesv.u[3] = 0x3F803F80u;

  float mm[2] = {-1e30f, -1e30f};
  f32x4 oacc[2][4] = {};
  f32x4 oaccS[2] = {};                            // row-sums, C-layout

  bf16x8 kA[4], vA[4], kB[4], vB[4], kC[4], vC[4], kD[4], vD[4];
  LOADKV(kA, vA, 0);
  LOADKV(kB, vB, 4096);

  constexpr int TB_END = 64 * 4096;               // 64 tiles x 4 KB
  for (int tb = 0; tb < TB_END; tb += 4 * 4096) {
    LOADKV(kC, vC, tb + 2 * 4096);
    LOADKV(kD, vD, tb + 3 * 4096);
    COMPUTE(kA, vA);
    COMPUTE(kB, vB);
    {
      const int tn = (tb + 4 * 4096 < TB_END) ? tb + 4 * 4096 : 0;  // tail wrap
      LOADKV(kA, vA, tn);
      LOADKV(kB, vB, tn + 4096);
    }
    COMPUTE(kC, vC);
    COMPUTE(kD, vD);
  }

  // epilogue: inv row-sum is already per-lane in C-layout (no shuffles)
#pragma unroll
  for (int qi = 0; qi < 2; ++qi) {
    float invR[4];
#pragma unroll
    for (int r = 0; r < 4; ++r) invR[r] = 1.0f / oaccS[qi][r];
#pragma unroll
    for (int df = 0; df < 4; ++df)
#pragma unroll
      for (int r = 0; r < 4; ++r) {
        const int row = qbase + qi * 16 + 4 * lg + r;
        const int e = h * 64 + df * 16 + ll;
        vec[((size_t)row * 2 + b) * 1024 + e] =
            __float2bfloat16(oacc[qi][df][r] * invR[r]);
      }
  }
}

// --------------------- residual add + LayerNorm (fused) ---------------------
__global__ __launch_bounds__(256)
void add_ln_kernel(const float* __restrict__ X, const float* __restrict__ Yadd,
                   const float* __restrict__ g, const float* __restrict__ bb,
                   float* __restrict__ out_f32,
                   __hip_bfloat16* __restrict__ out_b16) {
  const int row = blockIdx.x, t = threadIdx.x;
  const float4 x4 = *(const float4*)(X + (size_t)row * 1024 + t * 4);
  const float4 a4 = *(const float4*)(Yadd + (size_t)row * 1024 + t * 4);
  float v[4] = {x4.x + a4.x, x4.y + a4.y, x4.z + a4.z, x4.w + a4.w};
  float s = v[0] + v[1] + v[2] + v[3];
  float s2 = v[0] * v[0] + v[1] * v[1] + v[2] * v[2] + v[3] * v[3];
#pragma unroll
  for (int off = 1; off < 64; off <<= 1) {
    s += __shfl_xor(s, off);
    s2 += __shfl_xor(s2, off);
  }
  __shared__ float rs[4], rs2[4];
  if ((t & 63) == 0) { rs[t >> 6] = s; rs2[t >> 6] = s2; }
  __syncthreads();
  const float tot = rs[0] + rs[1] + rs[2] + rs[3];
  const float tot2 = rs2[0] + rs2[1] + rs2[2] + rs2[3];
  const float mu = tot * (1.0f / 1024.0f);
  const float var = tot2 * (1.0f / 1024.0f) - mu * mu;
  const float rstd = rsqrtf(var + 1e-5f);
  const float4 g4 = *(const float4*)(g + t * 4);
  const float4 b4 = *(const float4*)(bb + t * 4);
  float y[4];
  y[0] = (v[0] - mu) * rstd * g4.x + b4.x;
  y[1] = (v[1] - mu) * rstd * g4.y + b4.y;
  y[2] = (v[2] - mu) * rstd * g4.z + b4.z;
  y[3] = (v[3] - mu) * rstd * g4.w + b4.w;
  *(float4*)(out_f32 + (size_t)row * 1024 + t * 4) =
      make_float4(y[0], y[1], y[2], y[3]);
  __hip_bfloat16 tmp[4] = {__float2bfloat16(y[0]), __float2bfloat16(y[1]),
                           __float2bfloat16(y[2]), __float2bfloat16(y[3])};
  *(uint2*)(out_b16 + (size_t)row * 1024 + t * 4) = *(uint2*)tmp;
}

// ---------------- residual add + LayerNorm + 2*y + pe (final) ---------------
__global__ __launch_bounds__(256)
void final_kernel(const float* __restrict__ X, const float* __restrict__ Yadd,
                  const float* __restrict__ g, const float* __restrict__ bb,
                  const float* __restrict__ pe, float* __restrict__ out) {
  const int row = blockIdx.x, t = threadIdx.x;
  const float4 x4 = *(const float4*)(X + (size_t)row * 1024 + t * 4);
  const float4 a4 = *(const float4*)(Yadd + (size_t)row * 1024 + t * 4);
  float v[4] = {x4.x + a4.x, x4.y + a4.y, x4.z + a4.z, x4.w + a4.w};
  float s = v[0] + v[1] + v[2] + v[3];
  float s2 = v[0] * v[0] + v[1] * v[1] + v[2] * v[2] + v[3] * v[3];
#pragma unroll
  for (int off = 1; off < 64; off <<= 1) {
    s += __shfl_xor(s, off);
    s2 += __shfl_xor(s2, off);
  }
  __shared__ float rs[4], rs2[4];
  if ((t & 63) == 0) { rs[t >> 6] = s; rs2[t >> 6] = s2; }
  __syncthreads();
  const float tot = rs[0] + rs[1] + rs[2] + rs[3];
  const float tot2 = rs2[0] + rs2[1] + rs2[2] + rs2[3];
  const float mu = tot * (1.0f / 1024.0f);
  const float var = tot2 * (1.0f / 1024.0f) - mu * mu;
  const float rstd = rsqrtf(var + 1e-5f);
  const float4 g4 = *(const float4*)(g + t * 4);
  const float4 b4 = *(const float4*)(bb + t * 4);
  const int bidx = row & 1;
  const float4 p4 = *(const float4*)(pe + bidx * 1024 + t * 4);
  float y[4];
  y[0] = 2.0f * ((v[0] - mu) * rstd * g4.x + b4.x) + p4.x;
  y[1] = 2.0f * ((v[1] - mu) * rstd * g4.y + b4.y) + p4.y;
  y[2] = 2.0f * ((v[2] - mu) * rstd * g4.z + b4.z) + p4.z;
  y[3] = 2.0f * ((v[3] - mu) * rstd * g4.w + b4.w) + p4.w;
  *(float4*)(out + (size_t)row * 1024 + t * 4) = make_float4(y[0], y[1], y[2], y[3]);
}

// ---------------------------------------------------------------------------
extern "C" void kernel_launch(void* const* d_in, const int* in_sizes, int n_in,
                              void* d_out, int out_size, void* d_ws,
                              size_t ws_size, hipStream_t stream) {
  const float* x   = (const float*)d_in[0];
  const float* Wq  = (const float*)d_in[1];
  const float* Wkv = (const float*)d_in[2];
  const float* Wo  = (const float*)d_in[3];
  const float* g1  = (const float*)d_in[4];
  const float* b1  = (const float*)d_in[5];
  const float* Wff = (const float*)d_in[6];
  const float* g2  = (const float*)d_in[7];
  const float* b2  = (const float*)d_in[8];

  char* ws = (char*)d_ws;
  __hip_bfloat16* Wqkv_b = (__hip_bfloat16*)(ws + 0);          // 6 MB
  __hip_bfloat16* Wo_b   = (__hip_bfloat16*)(ws + 6 * WS_MB);  // 2 MB
  __hip_bfloat16* Wff_b  = (__hip_bfloat16*)(ws + 8 * WS_MB);  // 2 MB
  __hip_bfloat16* Xb     = (__hip_bfloat16*)(ws + 10 * WS_MB); // 8 MB
  __hip_bfloat16* Qb     = (__hip_bfloat16*)(ws + 18 * WS_MB); // 8 MB
  __hip_bfloat16* Kb     = (__hip_bfloat16*)(ws + 26 * WS_MB); // 8 MB (frag layout)
  __hip_bfloat16* VTb    = (__hip_bfloat16*)(ws + 34 * WS_MB); // 8 MB (frag layout)
  __hip_bfloat16* vecb   = (__hip_bfloat16*)(ws + 42 * WS_MB); // 8 MB
  float* attn            = (float*)(ws + 18 * WS_MB);          // 16 MB (alias Q+K)
  float* out1            = (float*)(ws + 50 * WS_MB);          // 16 MB
  __hip_bfloat16* out1b  = (__hip_bfloat16*)(ws + 66 * WS_MB); // 8 MB
  float* ffb             = (float*)(ws + 34 * WS_MB);          // 16 MB (alias VT+vec)
  float* pe              = (float*)(ws + 74 * WS_MB);          // 8 KB

  cvt_f32_bf16<<<4096, 256, 0, stream>>>(x, Xb, 1048576);
  cvt_f32_bf16<<<1024, 256, 0, stream>>>(Wq, Wqkv_b, 262144);
  cvt_f32_bf16<<<2048, 256, 0, stream>>>(Wkv, Wqkv_b + 1024 * 1024, 524288);
  cvt_f32_bf16<<<1024, 256, 0, stream>>>(Wo, Wo_b, 262144);
  cvt_f32_bf16<<<1024, 256, 0, stream>>>(Wff, Wff_b, 262144);
  pe_kernel<<<1, 512, 0, stream>>>(pe);

  gemm_bt<1><<<dim3(24, 32), 256, 0, stream>>>(Xb, Wqkv_b, nullptr, Qb, Kb, VTb,
                                               3072, 1024);
  attn_kernel<<<dim3(512), 256, 0, stream>>>(Qb, Kb, VTb, vecb);
  gemm_bt<0><<<dim3(8, 32), 256, 0, stream>>>(vecb, Wo_b, attn, nullptr, nullptr,
                                              nullptr, 1024, 1024);
  add_ln_kernel<<<4096, 256, 0, stream>>>(x, attn, g1, b1, out1, out1b);
  gemm_bt<0><<<dim3(8, 32), 256, 0, stream>>>(out1b, Wff_b, ffb, nullptr, nullptr,
                                              nullptr, 1024, 1024);
  final_kernel<<<4096, 256, 0, stream>>>(out1, ffb, g2, b2, pe, (float*)d_out);
}

// Round 8
// 191.810 us; speedup vs baseline: 2.0282x; 1.0882x over previous
//
#include <hip/hip_runtime.h>
#include <hip/hip_bf16.h>
#include <math.h>

// ---------------------------------------------------------------------------
// UpdateAttn: decoder block = QKV proj -> MHA (no mask) -> Wo + res + LN1
//             -> Wff + res + LN2 -> 2*out + pos_emb(batch)
// S=2048 B=2 D=1024 H=16 DH=64.  All GEMMs bf16 MFMA; residual/LN in f32.
// R7: (1) attn K/V staged through LDS double-buffer (global_load_lds once per
//     block, ds_read per wave) -> 4x less L1 traffic, frees prefetch VGPRs.
//     (2) all f32->bf16 weight/activation cvts + pe fused into one kernel.
// ---------------------------------------------------------------------------

typedef __bf16 bf16x8 __attribute__((ext_vector_type(8)));
typedef float f32x4  __attribute__((ext_vector_type(4)));

typedef const __attribute__((address_space(1))) unsigned int as1_uint;
typedef __attribute__((address_space(3))) unsigned int as3_uint;

constexpr int S_SEQ = 2048;
constexpr int DH    = 64;

#define WS_MB (1ull << 20)

__device__ __forceinline__ void gload16(void* lds, const void* g) {
  __builtin_amdgcn_global_load_lds((as1_uint*)g, (as3_uint*)lds, 16, 0, 0);
}

__device__ __forceinline__ float fast_exp2(float x) {
  float r;
  asm volatile("v_exp_f32 %0, %1\n\ts_nop 1" : "=v"(r) : "v"(x));
  return r;
}
__device__ __forceinline__ unsigned cvt_pk_bf16(float lo, float hi) {
  unsigned r;
  asm("v_cvt_pk_bf16_f32 %0, %1, %2" : "=v"(r) : "v"(lo), "v"(hi));
  return r;
}

// ------------------- fused f32->bf16 converts + pos table -------------------
__device__ __forceinline__ void cvt4(const float* __restrict__ in,
                                     __hip_bfloat16* __restrict__ out, int idx) {
  float4 v = ((const float4*)in)[idx];
  unsigned u0 = cvt_pk_bf16(v.x, v.y);
  unsigned u1 = cvt_pk_bf16(v.z, v.w);
  uint2 p; p.x = u0; p.y = u1;
  *(uint2*)(out + (size_t)idx * 4) = p;
}

__global__ __launch_bounds__(256)
void prep_kernel(const float* __restrict__ x, const float* __restrict__ Wq,
                 const float* __restrict__ Wkv, const float* __restrict__ Wo,
                 const float* __restrict__ Wff,
                 __hip_bfloat16* __restrict__ Xb,
                 __hip_bfloat16* __restrict__ Wqkv_b,
                 __hip_bfloat16* __restrict__ Wo_b,
                 __hip_bfloat16* __restrict__ Wff_b,
                 float* __restrict__ pe) {
  const int bid = blockIdx.x, t = threadIdx.x;
  if (bid < 4096) {
    cvt4(x, Xb, bid * 256 + t);
  } else if (bid < 5120) {
    cvt4(Wq, Wqkv_b, (bid - 4096) * 256 + t);
  } else if (bid < 7168) {
    cvt4(Wkv, Wqkv_b + 1024 * 1024, (bid - 5120) * 256 + t);
  } else if (bid < 8192) {
    cvt4(Wo, Wo_b, (bid - 7168) * 256 + t);
  } else if (bid < 9216) {
    cvt4(Wff, Wff_b, (bid - 8192) * 256 + t);
  } else {
#pragma unroll
    for (int rep = 0; rep < 2; ++rep) {
      const int k = rep * 256 + t;
      float freq = expf(-(2.0f * (float)k / 1024.0f) * logf(10000.0f));
      pe[2 * k]            = 0.0f;          // pos 0: sin(0)
      pe[2 * k + 1]        = 1.0f;          // pos 0: cos(0)
      pe[1024 + 2 * k]     = sinf(freq);    // pos 1
      pe[1024 + 2 * k + 1] = cosf(freq);
    }
  }
}

// ------------------------------ GEMM (B^T) ---------------------------------
// MODE 1 scatter targets (fragment-contiguous K/V for attn):
//   Q : Qb[bh][i][dh]
//   K : Kf[bh][tile][instr][lane][8]   (attn kk[instr] fragment order)
//   V : Vf[bh][tile][df][lane][8]      (attn vv[df] fragment order)
template <int MODE>
__global__ __launch_bounds__(256)
void gemm_bt(const __hip_bfloat16* __restrict__ A,
             const __hip_bfloat16* __restrict__ Bw,
             float* __restrict__ C,
             __hip_bfloat16* __restrict__ Qb,
             __hip_bfloat16* __restrict__ Kb,
             __hip_bfloat16* __restrict__ VTb,
             int Ndim, int Kdim) {
  constexpr int BK = 64;
  __shared__ __hip_bfloat16 sA[128 * BK];
  __shared__ __hip_bfloat16 sB[128 * BK];
  const int t = threadIdx.x, w = t >> 6, l = t & 63;
  const int bm = blockIdx.y * 128, bn = blockIdx.x * 128;
  const int m0 = (w >> 1) * 64, n0 = (w & 1) * 64;
  const int lrow = l >> 3, lcol = l & 7;
  const int ll = l & 15, lg = l >> 4;

  f32x4 acc[4][4] = {};

  for (int kt = 0; kt < Kdim; kt += BK) {
    __syncthreads();
#pragma unroll
    for (int r = 0; r < 4; ++r) {
      const int chunk = r * 4 + w;
      const int row = chunk * 8 + lrow;
      gload16((char*)sA + chunk * 1024 + l * 16,
              A + (size_t)(bm + row) * Kdim + kt + lcol * 8);
      gload16((char*)sB + chunk * 1024 + l * 16,
              Bw + (size_t)(bn + row) * Kdim + kt + lcol * 8);
    }
    __syncthreads();
#pragma unroll
    for (int ks = 0; ks < 2; ++ks) {
      bf16x8 a[4], b[4];
#pragma unroll
      for (int mi = 0; mi < 4; ++mi)
        a[mi] = *(const bf16x8*)((const char*)sA +
                 (m0 + mi * 16 + ll) * 128 + ks * 64 + lg * 16);
#pragma unroll
      for (int ni = 0; ni < 4; ++ni)
        b[ni] = *(const bf16x8*)((const char*)sB +
                 (n0 + ni * 16 + ll) * 128 + ks * 64 + lg * 16);
#pragma unroll
      for (int mi = 0; mi < 4; ++mi)
#pragma unroll
        for (int ni = 0; ni < 4; ++ni)
          acc[mi][ni] = __builtin_amdgcn_mfma_f32_16x16x32_bf16(
              a[mi], b[ni], acc[mi][ni], 0, 0, 0);
    }
  }

#pragma unroll
  for (int mi = 0; mi < 4; ++mi)
#pragma unroll
    for (int ni = 0; ni < 4; ++ni)
#pragma unroll
      for (int r = 0; r < 4; ++r) {
        const int gm = bm + m0 + mi * 16 + lg * 4 + r;
        const int gn = bn + n0 + ni * 16 + ll;
        const float v = acc[mi][ni][r];
        if (MODE == 0) {
          C[(size_t)gm * Ndim + gn] = v;
        } else {
          const int i = gm >> 1, bb = gm & 1;
          const __hip_bfloat16 hv = __float2bfloat16(v);
          if (gn < 1024) {
            const int h = gn >> 6, dh = gn & 63;
            Qb[(((size_t)(bb * 16 + h)) * 2048 + i) * 64 + dh] = hv;
          } else if (gn < 2048) {
            const int e = gn - 1024, h = e >> 6, dh = e & 63;
            const int bh2 = bb * 16 + h;
            const int tile = i >> 5, r32 = i & 31;
            const int a8 = r32 & 7, b8 = r32 >> 3;
            const int hi = dh >> 5, w32 = dh & 31;
            const int lg2 = w32 >> 3, be = w32 & 7;
            const int ll2 = b8 * 4 + (a8 & 3);
            const int instr = (a8 < 4 ? 0 : 2) + hi;
            const int lane = lg2 * 16 + ll2;
            Kb[(size_t)bh2 * 131072 + tile * 2048 + instr * 512 + lane * 8 + be] = hv;
          } else {
            const int e = gn - 2048, h = e >> 6, dh = e & 63;
            const int bh2 = bb * 16 + h;
            const int tile = i >> 5, r32 = i & 31;
            const int lg2 = r32 >> 3, e8 = r32 & 7;
            const int ll2 = dh & 15, df = dh >> 4;
            const int lane = lg2 * 16 + ll2;
            VTb[(size_t)bh2 * 131072 + tile * 2048 + df * 512 + lane * 8 + e8] = hv;
          }
        }
      }
}

// ----------------------------- flash attention ------------------------------
// Single pass, online softmax with defer-max; fragment-contiguous K/V staged
// through a 2x8KB LDS double-buffer: global_load_lds ONCE per block per tile,
// each wave ds_reads its fragments (stride-1, conflict-free).  512 blocks,
// XCD-grouped; wave owns 32 q-rows; row-sum via ones-B MFMA in C-layout.

#define MFMA_B16 __builtin_amdgcn_mfma_f32_16x16x32_bf16

#define STAGE(bufp, tb)                                                       \
  {                                                                           \
    gload16((bufp) + woff, Kf + (tb) + wl16);                                 \
    gload16((bufp) + 4096 + woff, Vf + (tb) + wl16);                          \
  }

#define COMPUTE(kk, vv)                                                       \
  {                                                                           \
    const f32x4 z = {0.f, 0.f, 0.f, 0.f};                                     \
    f32x4 s0[2], s1[2];                                                       \
    s0[0] = MFMA_B16(kk[0], qf[0][0], z, 0, 0, 0);                            \
    s0[0] = MFMA_B16(kk[1], qf[0][1], s0[0], 0, 0, 0);                        \
    s1[0] = MFMA_B16(kk[2], qf[0][0], z, 0, 0, 0);                            \
    s1[0] = MFMA_B16(kk[3], qf[0][1], s1[0], 0, 0, 0);                        \
    s0[1] = MFMA_B16(kk[0], qf[1][0], z, 0, 0, 0);                            \
    s0[1] = MFMA_B16(kk[1], qf[1][1], s0[1], 0, 0, 0);                        \
    s1[1] = MFMA_B16(kk[2], qf[1][0], z, 0, 0, 0);                            \
    s1[1] = MFMA_B16(kk[3], qf[1][1], s1[1], 0, 0, 0);                        \
    float plm[2];                                                             \
    _Pragma("unroll")                                                         \
    for (int qi = 0; qi < 2; ++qi) {                                          \
      float a = fmaxf(fmaxf(s0[qi][0], s0[qi][1]),                            \
                      fmaxf(s0[qi][2], s0[qi][3]));                           \
      float c = fmaxf(fmaxf(s1[qi][0], s1[qi][1]),                            \
                      fmaxf(s1[qi][2], s1[qi][3]));                           \
      plm[qi] = fmaxf(a, c) * C1;                                             \
    }                                                                         \
    if (__any((plm[0] > mm[0] + THR2) || (plm[1] > mm[1] + THR2))) {          \
      _Pragma("unroll")                                                       \
      for (int qi = 0; qi < 2; ++qi) {                                        \
        float pm = plm[qi];                                                   \
        pm = fmaxf(pm, __shfl_xor(pm, 16));                                   \
        pm = fmaxf(pm, __shfl_xor(pm, 32));                                   \
        const float nm = fmaxf(mm[qi], pm);                                   \
        const float al = fast_exp2(mm[qi] - nm);                              \
        mm[qi] = nm;                                                          \
        float aR[4];                                                          \
        _Pragma("unroll")                                                     \
        for (int r = 0; r < 4; ++r) aR[r] = __shfl(al, 4 * lg + r);           \
        _Pragma("unroll")                                                     \
        for (int df = 0; df < 4; ++df)                                        \
          _Pragma("unroll")                                                   \
          for (int r = 0; r < 4; ++r) oacc[qi][df][r] *= aR[r];               \
        _Pragma("unroll")                                                     \
        for (int r = 0; r < 4; ++r) oaccS[qi][r] *= aR[r];                    \
      }                                                                       \
    }                                                                         \
    _Pragma("unroll")                                                         \
    for (int qi = 0; qi < 2; ++qi) {                                          \
      float p[8];                                                             \
      _Pragma("unroll")                                                       \
      for (int r = 0; r < 4; ++r) {                                           \
        p[r]     = fast_exp2(fmaf(s0[qi][r], C1, -mm[qi]));                   \
        p[4 + r] = fast_exp2(fmaf(s1[qi][r], C1, -mm[qi]));                   \
      }                                                                       \
      union { unsigned u[4]; bf16x8 v; } pk;                                  \
      pk.u[0] = cvt_pk_bf16(p[0], p[1]);                                      \
      pk.u[1] = cvt_pk_bf16(p[2], p[3]);                                      \
      pk.u[2] = cvt_pk_bf16(p[4], p[5]);                                      \
      pk.u[3] = cvt_pk_bf16(p[6], p[7]);                                      \
      _Pragma("unroll")                                                       \
      for (int df = 0; df < 4; ++df)                                          \
        oacc[qi][df] = MFMA_B16(pk.v, vv[df], oacc[qi][df], 0, 0, 0);         \
      oaccS[qi] = MFMA_B16(pk.v, onesv.v, oaccS[qi], 0, 0, 0);                \
    }                                                                         \
  }

__global__ __launch_bounds__(256)
void attn_kernel(const __hip_bfloat16* __restrict__ Qb,
                 const __hip_bfloat16* __restrict__ Kb,
                 const __hip_bfloat16* __restrict__ VTb,
                 __hip_bfloat16* __restrict__ vec) {
  __shared__ __align__(16) char lds0[8192];
  __shared__ __align__(16) char lds1[8192];
  const int t = threadIdx.x, w = t >> 6, l = t & 63;
  // 512 blocks; xcd = bid&7 owns a fixed group of 4 bh; qt = 0..15.
  const int bid = blockIdx.x;
  const int slot = bid >> 3;
  const int bh = (bid & 7) * 4 + (slot & 3);
  const int qt = slot >> 2;                       // 0..15
  const int b = bh >> 4, h = bh & 15;
  const __hip_bfloat16* Q = Qb + (size_t)bh * S_SEQ * DH;
  const char* Kf = (const char*)Kb + (size_t)bh * 262144;   // 256 KB / bh
  const char* Vf = (const char*)VTb + (size_t)bh * 262144;
  const int ll = l & 15, lg = l >> 4;
  const int l16 = l * 16;
  const int woff = w * 1024 + l16;                // this wave's staging chunk
  const int wl16 = woff;                          // same linear offset in src
  constexpr float C1   = 0.125f * 1.44269504088896f;  // scale * log2(e)
  constexpr float THR2 = 11.5416f;                    // 8 nats in exp2 domain

  const int qbase = qt * 128 + w * 32;
  bf16x8 qf[2][2];
#pragma unroll
  for (int qi = 0; qi < 2; ++qi) {
    qf[qi][0] = *(const bf16x8*)(Q + (size_t)(qbase + qi * 16 + ll) * 64 + lg * 8);
    qf[qi][1] = *(const bf16x8*)(Q + (size_t)(qbase + qi * 16 + ll) * 64 + 32 + lg * 8);
  }

  union { unsigned u[4]; bf16x8 v; } onesv;       // bf16 1.0 x8
  onesv.u[0] = 0x3F803F80u; onesv.u[1] = 0x3F803F80u;
  onesv.u[2] = 0x3F803F80u; onesv.u[3] = 0x3F803F80u;

  float mm[2] = {-1e30f, -1e30f};
  f32x4 oacc[2][4] = {};
  f32x4 oaccS[2] = {};                            // row-sums, C-layout

  STAGE(lds0, 0);

  for (int tile = 0; tile < 64; ++tile) {
    __syncthreads();                              // stage done + prev reads done
    const char* cur = (tile & 1) ? lds1 : lds0;
    char* nxt       = (tile & 1) ? lds0 : lds1;
    if (tile < 63) STAGE(nxt, (tile + 1) * 4096); // async prefetch next tile
    bf16x8 kk[4], vv[4];
#pragma unroll
    for (int i = 0; i < 4; ++i) {
      kk[i] = *(const bf16x8*)(cur + i * 1024 + l16);
      vv[i] = *(const bf16x8*)(cur + 4096 + i * 1024 + l16);
    }
    COMPUTE(kk, vv);
  }

  // epilogue: inv row-sum is already per-lane in C-layout (no shuffles)
#pragma unroll
  for (int qi = 0; qi < 2; ++qi) {
    float invR[4];
#pragma unroll
    for (int r = 0; r < 4; ++r) invR[r] = 1.0f / oaccS[qi][r];
#pragma unroll
    for (int df = 0; df < 4; ++df)
#pragma unroll
      for (int r = 0; r < 4; ++r) {
        const int row = qbase + qi * 16 + 4 * lg + r;
        const int e = h * 64 + df * 16 + ll;
        vec[((size_t)row * 2 + b) * 1024 + e] =
            __float2bfloat16(oacc[qi][df][r] * invR[r]);
      }
  }
}

// --------------------- residual add + LayerNorm (fused) ---------------------
__global__ __launch_bounds__(256)
void add_ln_kernel(const float* __restrict__ X, const float* __restrict__ Yadd,
                   const float* __restrict__ g, const float* __restrict__ bb,
                   float* __restrict__ out_f32,
                   __hip_bfloat16* __restrict__ out_b16) {
  const int row = blockIdx.x, t = threadIdx.x;
  const float4 x4 = *(const float4*)(X + (size_t)row * 1024 + t * 4);
  const float4 a4 = *(const float4*)(Yadd + (size_t)row * 1024 + t * 4);
  float v[4] = {x4.x + a4.x, x4.y + a4.y, x4.z + a4.z, x4.w + a4.w};
  float s = v[0] + v[1] + v[2] + v[3];
  float s2 = v[0] * v[0] + v[1] * v[1] + v[2] * v[2] + v[3] * v[3];
#pragma unroll
  for (int off = 1; off < 64; off <<= 1) {
    s += __shfl_xor(s, off);
    s2 += __shfl_xor(s2, off);
  }
  __shared__ float rs[4], rs2[4];
  if ((t & 63) == 0) { rs[t >> 6] = s; rs2[t >> 6] = s2; }
  __syncthreads();
  const float tot = rs[0] + rs[1] + rs[2] + rs[3];
  const float tot2 = rs2[0] + rs2[1] + rs2[2] + rs2[3];
  const float mu = tot * (1.0f / 1024.0f);
  const float var = tot2 * (1.0f / 1024.0f) - mu * mu;
  const float rstd = rsqrtf(var + 1e-5f);
  const float4 g4 = *(const float4*)(g + t * 4);
  const float4 b4 = *(const float4*)(bb + t * 4);
  float y[4];
  y[0] = (v[0] - mu) * rstd * g4.x + b4.x;
  y[1] = (v[1] - mu) * rstd * g4.y + b4.y;
  y[2] = (v[2] - mu) * rstd * g4.z + b4.z;
  y[3] = (v[3] - mu) * rstd * g4.w + b4.w;
  *(float4*)(out_f32 + (size_t)row * 1024 + t * 4) =
      make_float4(y[0], y[1], y[2], y[3]);
  uint2 pk2;
  pk2.x = cvt_pk_bf16(y[0], y[1]);
  pk2.y = cvt_pk_bf16(y[2], y[3]);
  *(uint2*)(out_b16 + (size_t)row * 1024 + t * 4) = pk2;
}

// ---------------- residual add + LayerNorm + 2*y + pe (final) ---------------
__global__ __launch_bounds__(256)
void final_kernel(const float* __restrict__ X, const float* __restrict__ Yadd,
                  const float* __restrict__ g, const float* __restrict__ bb,
                  const float* __restrict__ pe, float* __restrict__ out) {
  const int row = blockIdx.x, t = threadIdx.x;
  const float4 x4 = *(const float4*)(X + (size_t)row * 1024 + t * 4);
  const float4 a4 = *(const float4*)(Yadd + (size_t)row * 1024 + t * 4);
  float v[4] = {x4.x + a4.x, x4.y + a4.y, x4.z + a4.z, x4.w + a4.w};
  float s = v[0] + v[1] + v[2] + v[3];
  float s2 = v[0] * v[0] + v[1] * v[1] + v[2] * v[2] + v[3] * v[3];
#pragma unroll
  for (int off = 1; off < 64; off <<= 1) {
    s += __shfl_xor(s, off);
    s2 += __shfl_xor(s2, off);
  }
  __shared__ float rs[4], rs2[4];
  if ((t & 63) == 0) { rs[t >> 6] = s; rs2[t >> 6] = s2; }
  __syncthreads();
  const float tot = rs[0] + rs[1] + rs[2] + rs[3];
  const float tot2 = rs2[0] + rs2[1] + rs2[2] + rs2[3];
  const float mu = tot * (1.0f / 1024.0f);
  const float var = tot2 * (1.0f / 1024.0f) - mu * mu;
  const float rstd = rsqrtf(var + 1e-5f);
  const float4 g4 = *(const float4*)(g + t * 4);
  const float4 b4 = *(const float4*)(bb + t * 4);
  const int bidx = row & 1;
  const float4 p4 = *(const float4*)(pe + bidx * 1024 + t * 4);
  float y[4];
  y[0] = 2.0f * ((v[0] - mu) * rstd * g4.x + b4.x) + p4.x;
  y[1] = 2.0f * ((v[1] - mu) * rstd * g4.y + b4.y) + p4.y;
  y[2] = 2.0f * ((v[2] - mu) * rstd * g4.z + b4.z) + p4.z;
  y[3] = 2.0f * ((v[3] - mu) * rstd * g4.w + b4.w) + p4.w;
  *(float4*)(out + (size_t)row * 1024 + t * 4) = make_float4(y[0], y[1], y[2], y[3]);
}

// ---------------------------------------------------------------------------
extern "C" void kernel_launch(void* const* d_in, const int* in_sizes, int n_in,
                              void* d_out, int out_size, void* d_ws,
                              size_t ws_size, hipStream_t stream) {
  const float* x   = (const float*)d_in[0];
  const float* Wq  = (const float*)d_in[1];
  const float* Wkv = (const float*)d_in[2];
  const float* Wo  = (const float*)d_in[3];
  const float* g1  = (const float*)d_in[4];
  const float* b1  = (const float*)d_in[5];
  const float* Wff = (const float*)d_in[6];
  const float* g2  = (const float*)d_in[7];
  const float* b2  = (const float*)d_in[8];

  char* ws = (char*)d_ws;
  __hip_bfloat16* Wqkv_b = (__hip_bfloat16*)(ws + 0);          // 6 MB
  __hip_bfloat16* Wo_b   = (__hip_bfloat16*)(ws + 6 * WS_MB);  // 2 MB
  __hip_bfloat16* Wff_b  = (__hip_bfloat16*)(ws + 8 * WS_MB);  // 2 MB
  __hip_bfloat16* Xb     = (__hip_bfloat16*)(ws + 10 * WS_MB); // 8 MB
  __hip_bfloat16* Qb     = (__hip_bfloat16*)(ws + 18 * WS_MB); // 8 MB
  __hip_bfloat16* Kb     = (__hip_bfloat16*)(ws + 26 * WS_MB); // 8 MB (frag layout)
  __hip_bfloat16* VTb    = (__hip_bfloat16*)(ws + 34 * WS_MB); // 8 MB (frag layout)
  __hip_bfloat16* vecb   = (__hip_bfloat16*)(ws + 42 * WS_MB); // 8 MB
  float* attn            = (float*)(ws + 18 * WS_MB);          // 16 MB (alias Q+K)
  float* out1            = (float*)(ws + 50 * WS_MB);          // 16 MB
  __hip_bfloat16* out1b  = (__hip_bfloat16*)(ws + 66 * WS_MB); // 8 MB
  float* ffb             = (float*)(ws + 34 * WS_MB);          // 16 MB (alias VT+vec)
  float* pe              = (float*)(ws + 74 * WS_MB);          // 8 KB

  prep_kernel<<<9217, 256, 0, stream>>>(x, Wq, Wkv, Wo, Wff, Xb, Wqkv_b,
                                        Wo_b, Wff_b, pe);
  gemm_bt<1><<<dim3(24, 32), 256, 0, stream>>>(Xb, Wqkv_b, nullptr, Qb, Kb, VTb,
                                               3072, 1024);
  attn_kernel<<<dim3(512), 256, 0, stream>>>(Qb, Kb, VTb, vecb);
  gemm_bt<0><<<dim3(8, 32), 256, 0, stream>>>(vecb, Wo_b, attn, nullptr, nullptr,
                                              nullptr, 1024, 1024);
  add_ln_kernel<<<4096, 256, 0, stream>>>(x, attn, g1, b1, out1, out1b);
  gemm_bt<0><<<dim3(8, 32), 256, 0, stream>>>(out1b, Wff_b, ffb, nullptr, nullptr,
                                              nullptr, 1024, 1024);
  final_kernel<<<4096, 256, 0, stream>>>(out1, ffb, g2, b2, pe, (float*)d_out);
}

// Round 10
// 163.081 us; speedup vs baseline: 2.3855x; 1.1762x over previous
//
#include <hip/hip_runtime.h>
#include <hip/hip_bf16.h>
#include <math.h>

// ---------------------------------------------------------------------------
// UpdateAttn: decoder block = QKV proj -> MHA (no mask) -> Wo + res + LN1
//             -> Wff + res + LN2 -> 2*out + pos_emb(batch)
// S=2048 B=2 D=1024 H=16 DH=64.  All GEMMs bf16 MFMA; residual/LN in f32.
// R9: R8 + fix B-tile staging bound (BN/64 -> BN/32; R8 staged only half the
//     B tile -> NaN).  GEMM: double-buffered LDS, one barrier per K-step.
//     QKV epilogue: LDS-image + 16B coalesced stores.  Wo/Wff: 128x64 tiles.
// ---------------------------------------------------------------------------

typedef __bf16 bf16x8 __attribute__((ext_vector_type(8)));
typedef float f32x4  __attribute__((ext_vector_type(4)));

typedef const __attribute__((address_space(1))) unsigned int as1_uint;
typedef __attribute__((address_space(3))) unsigned int as3_uint;

constexpr int S_SEQ = 2048;
constexpr int DH    = 64;

#define WS_MB (1ull << 20)

__device__ __forceinline__ void gload16(void* lds, const void* g) {
  __builtin_amdgcn_global_load_lds((as1_uint*)g, (as3_uint*)lds, 16, 0, 0);
}

__device__ __forceinline__ float fast_exp2(float x) {
  float r;
  asm volatile("v_exp_f32 %0, %1\n\ts_nop 1" : "=v"(r) : "v"(x));
  return r;
}
__device__ __forceinline__ unsigned cvt_pk_bf16(float lo, float hi) {
  unsigned r;
  asm("v_cvt_pk_bf16_f32 %0, %1, %2" : "=v"(r) : "v"(lo), "v"(hi));
  return r;
}

// ------------------- fused f32->bf16 converts + pos table -------------------
__device__ __forceinline__ void cvt4(const float* __restrict__ in,
                                     __hip_bfloat16* __restrict__ out, int idx) {
  float4 v = ((const float4*)in)[idx];
  uint2 p;
  p.x = cvt_pk_bf16(v.x, v.y);
  p.y = cvt_pk_bf16(v.z, v.w);
  *(uint2*)(out + (size_t)idx * 4) = p;
}

__global__ __launch_bounds__(256)
void prep_kernel(const float* __restrict__ x, const float* __restrict__ Wq,
                 const float* __restrict__ Wkv, const float* __restrict__ Wo,
                 const float* __restrict__ Wff,
                 __hip_bfloat16* __restrict__ Xb,
                 __hip_bfloat16* __restrict__ Wqkv_b,
                 __hip_bfloat16* __restrict__ Wo_b,
                 __hip_bfloat16* __restrict__ Wff_b,
                 float* __restrict__ pe) {
  const int bid = blockIdx.x, t = threadIdx.x;
  if (bid < 4096) {
    cvt4(x, Xb, bid * 256 + t);
  } else if (bid < 5120) {
    cvt4(Wq, Wqkv_b, (bid - 4096) * 256 + t);
  } else if (bid < 7168) {
    cvt4(Wkv, Wqkv_b + 1024 * 1024, (bid - 5120) * 256 + t);
  } else if (bid < 8192) {
    cvt4(Wo, Wo_b, (bid - 7168) * 256 + t);
  } else if (bid < 9216) {
    cvt4(Wff, Wff_b, (bid - 8192) * 256 + t);
  } else {
#pragma unroll
    for (int rep = 0; rep < 2; ++rep) {
      const int k = rep * 256 + t;
      float freq = expf(-(2.0f * (float)k / 1024.0f) * logf(10000.0f));
      pe[2 * k]            = 0.0f;
      pe[2 * k + 1]        = 1.0f;
      pe[1024 + 2 * k]     = sinf(freq);
      pe[1024 + 2 * k + 1] = cosf(freq);
    }
  }
}

// ------------------------------ GEMM (B^T) ---------------------------------
// Double-buffered LDS, one barrier per K-step.  MODE 0: f32 C row-major,
// BN=64 tile (512 blocks for N=1024).  MODE 1 (BN=128): QKV epilogue through
// an LDS image -> fully coalesced 16B stores into fragment-contiguous K/V.
template <int MODE, int BN>
__global__ __launch_bounds__(256)
void gemm_bt(const __hip_bfloat16* __restrict__ A,
             const __hip_bfloat16* __restrict__ Bw,
             float* __restrict__ C,
             __hip_bfloat16* __restrict__ Qb,
             __hip_bfloat16* __restrict__ Kb,
             __hip_bfloat16* __restrict__ VTb,
             int Ndim, int Kdim) {
  constexpr int ASZ = 128 * 64 * 2;            // A tile bytes
  constexpr int BSZ = BN * 64 * 2;             // B tile bytes
  constexpr int NI  = BN / 32;                 // 4 (BN=128) or 2 (BN=64)
  __shared__ __align__(16) char smem[2 * (ASZ + BSZ)];
  const int t = threadIdx.x, w = t >> 6, l = t & 63;
  const int bm = blockIdx.y * 128, bn = blockIdx.x * BN;
  const int m0 = (w >> 1) * 64, n0 = (w & 1) * (BN / 2);
  const int lrow = l >> 3, lcol = l & 7;
  const int ll = l & 15, lg = l >> 4;

  auto stage = [&](char* buf, int kt) {
#pragma unroll
    for (int r = 0; r < 4; ++r) {              // A: 128 rows = 16 chunks
      const int chunk = r * 4 + w;
      const int row = chunk * 8 + lrow;
      gload16(buf + chunk * 1024 + l * 16,
              A + (size_t)(bm + row) * Kdim + kt + lcol * 8);
    }
#pragma unroll
    for (int r = 0; r < BN / 32; ++r) {        // B: BN rows = BN/8 chunks
      const int chunk = r * 4 + w;
      const int row = chunk * 8 + lrow;
      gload16(buf + ASZ + chunk * 1024 + l * 16,
              Bw + (size_t)(bn + row) * Kdim + kt + lcol * 8);
    }
  };

  f32x4 acc[4][NI] = {};

  stage(smem, 0);
  __syncthreads();                              // buf0 staged (vmcnt drained)
  int cur = 0;
  for (int kt = 0; kt < Kdim; kt += 64) {
    char* bufc = smem + cur * (ASZ + BSZ);
    if (kt + 64 < Kdim) stage(smem + (cur ^ 1) * (ASZ + BSZ), kt + 64);
    const char* sA = bufc;
    const char* sB = bufc + ASZ;
#pragma unroll
    for (int ks = 0; ks < 2; ++ks) {
      bf16x8 a[4], bfr[NI];
#pragma unroll
      for (int mi = 0; mi < 4; ++mi)
        a[mi] = *(const bf16x8*)(sA + (m0 + mi * 16 + ll) * 128 + ks * 64 + lg * 16);
#pragma unroll
      for (int ni = 0; ni < NI; ++ni)
        bfr[ni] = *(const bf16x8*)(sB + (n0 + ni * 16 + ll) * 128 + ks * 64 + lg * 16);
#pragma unroll
      for (int mi = 0; mi < 4; ++mi)
#pragma unroll
        for (int ni = 0; ni < NI; ++ni)
          acc[mi][ni] = __builtin_amdgcn_mfma_f32_16x16x32_bf16(
              a[mi], bfr[ni], acc[mi][ni], 0, 0, 0);
    }
    __syncthreads();   // drains this iter's stage (vmcnt) + cur-buffer reads done
    cur ^= 1;
  }

  if (MODE == 0) {
#pragma unroll
    for (int mi = 0; mi < 4; ++mi)
#pragma unroll
      for (int ni = 0; ni < NI; ++ni)
#pragma unroll
        for (int r = 0; r < 4; ++r) {
          const int gm = bm + m0 + mi * 16 + lg * 4 + r;
          const int gn = bn + n0 + ni * 16 + ll;
          C[(size_t)gm * Ndim + gn] = acc[mi][ni][r];
        }
  } else {
    // ---- stage acc into LDS image (region-specific layout), then coalesce --
    __hip_bfloat16* img = (__hip_bfloat16*)smem;   // 128 x 136 bf16 (padded)
    const bool isV = (bn >= 2048);
#pragma unroll
    for (int mi = 0; mi < 4; ++mi)
#pragma unroll
      for (int ni = 0; ni < NI; ++ni)
#pragma unroll
        for (int r = 0; r < 4; ++r) {
          const int gml = m0 + mi * 16 + lg * 4 + r;     // 0..127
          const int gnl = n0 + ni * 16 + ll;             // 0..127
          const int off = isV ? gnl * 136 + ((gml & 1) << 6) + (gml >> 1)
                              : gml * 136 + gnl;
          img[off] = __float2bfloat16(acc[mi][ni][r]);
        }
    __syncthreads();
    const int i0 = bm >> 1;        // seq base
    const int tile0 = bm >> 6;     // kv tile base
#pragma unroll
    for (int j = 0; j < 8; ++j) {
      const int c = j * 256 + t;   // chunk id, lane-consecutive
      uint4 val;
      __hip_bfloat16* dst;
      if (bn < 1024) {             // Q: [bh][i][dh]
        const int bb = c >> 10, hl = (c >> 9) & 1;
        const int q = c & 511, il = q >> 3, dh0 = (q & 7) * 8;
        val = *(const uint4*)&img[(il * 2 + bb) * 136 + hl * 64 + dh0];
        dst = Qb + ((size_t)(bb * 16 + (bn >> 6) + hl) * 2048 + i0 + il) * 64 + dh0;
      } else if (bn < 2048) {      // K fragment runs: [bh][tile][instr][lane][8]
        const int run = c >> 6, lane = c & 63;
        const int bb = run >> 4, hl = (run >> 3) & 1, th = (run >> 2) & 1,
                  instr = run & 3;
        const int lg2 = lane >> 4, ll2 = lane & 15;
        const int r32 = (ll2 >> 2) * 8 + (ll2 & 3) + ((instr >> 1) << 2);
        const int il = th * 32 + r32;
        const int dh0 = (instr & 1) * 32 + lg2 * 8;
        val = *(const uint4*)&img[(il * 2 + bb) * 136 + hl * 64 + dh0];
        dst = Kb + (size_t)(bb * 16 + ((bn - 1024) >> 6) + hl) * 131072 +
              (size_t)(tile0 + th) * 2048 + instr * 512 + lane * 8;
      } else {                     // V fragment runs: [bh][tile][df][lane][8]
        const int run = c >> 6, lane = c & 63;
        const int bb = run >> 4, hl = (run >> 3) & 1, th = (run >> 2) & 1,
                  df = run & 3;
        const int lg2 = lane >> 4, ll2 = lane & 15;
        const int il0 = th * 32 + lg2 * 8;
        const int gnl = hl * 64 + df * 16 + ll2;
        val = *(const uint4*)&img[gnl * 136 + bb * 64 + il0];
        dst = VTb + (size_t)(bb * 16 + ((bn - 2048) >> 6) + hl) * 131072 +
              (size_t)(tile0 + th) * 2048 + df * 512 + lane * 8;
      }
      *(uint4*)dst = val;
    }
  }
}

// ----------------------------- flash attention ------------------------------
// Single pass, online softmax with defer-max; fragment-contiguous K/V staged
// through a 2x8KB LDS double-buffer (global_load_lds once/block/tile).
// 512 blocks XCD-grouped; wave owns 32 q-rows; ones-MFMA row-sum in C-layout.

#define MFMA_B16 __builtin_amdgcn_mfma_f32_16x16x32_bf16

#define STAGE(bufp, tb)                                                       \
  {                                                                           \
    gload16((bufp) + woff, Kf + (tb) + wl16);                                 \
    gload16((bufp) + 4096 + woff, Vf + (tb) + wl16);                          \
  }

#define COMPUTE(kk, vv)                                                       \
  {                                                                           \
    const f32x4 z = {0.f, 0.f, 0.f, 0.f};                                     \
    f32x4 s0[2], s1[2];                                                       \
    s0[0] = MFMA_B16(kk[0], qf[0][0], z, 0, 0, 0);                            \
    s0[0] = MFMA_B16(kk[1], qf[0][1], s0[0], 0, 0, 0);                        \
    s1[0] = MFMA_B16(kk[2], qf[0][0], z, 0, 0, 0);                            \
    s1[0] = MFMA_B16(kk[3], qf[0][1], s1[0], 0, 0, 0);                        \
    s0[1] = MFMA_B16(kk[0], qf[1][0], z, 0, 0, 0);                            \
    s0[1] = MFMA_B16(kk[1], qf[1][1], s0[1], 0, 0, 0);                        \
    s1[1] = MFMA_B16(kk[2], qf[1][0], z, 0, 0, 0);                            \
    s1[1] = MFMA_B16(kk[3], qf[1][1], s1[1], 0, 0, 0);                        \
    float plm[2];                                                             \
    _Pragma("unroll")                                                         \
    for (int qi = 0; qi < 2; ++qi) {                                          \
      float a = fmaxf(fmaxf(s0[qi][0], s0[qi][1]),                            \
                      fmaxf(s0[qi][2], s0[qi][3]));                           \
      float c = fmaxf(fmaxf(s1[qi][0], s1[qi][1]),                            \
                      fmaxf(s1[qi][2], s1[qi][3]));                           \
      plm[qi] = fmaxf(a, c) * C1;                                             \
    }                                                                         \
    if (__any((plm[0] > mm[0] + THR2) || (plm[1] > mm[1] + THR2))) {          \
      _Pragma("unroll")                                                       \
      for (int qi = 0; qi < 2; ++qi) {                                        \
        float pm = plm[qi];                                                   \
        pm = fmaxf(pm, __shfl_xor(pm, 16));                                   \
        pm = fmaxf(pm, __shfl_xor(pm, 32));                                   \
        const float nm = fmaxf(mm[qi], pm);                                   \
        const float al = fast_exp2(mm[qi] - nm);                              \
        mm[qi] = nm;                                                          \
        float aR[4];                                                          \
        _Pragma("unroll")                                                     \
        for (int r = 0; r < 4; ++r) aR[r] = __shfl(al, 4 * lg + r);           \
        _Pragma("unroll")                                                     \
        for (int df = 0; df < 4; ++df)                                        \
          _Pragma("unroll")                                                   \
          for (int r = 0; r < 4; ++r) oacc[qi][df][r] *= aR[r];               \
        _Pragma("unroll")                                                     \
        for (int r = 0; r < 4; ++r) oaccS[qi][r] *= aR[r];                    \
      }                                                                       \
    }                                                                         \
    _Pragma("unroll")                                                         \
    for (int qi = 0; qi < 2; ++qi) {                                          \
      float p[8];                                                             \
      _Pragma("unroll")                                                       \
      for (int r = 0; r < 4; ++r) {                                           \
        p[r]     = fast_exp2(fmaf(s0[qi][r], C1, -mm[qi]));                   \
        p[4 + r] = fast_exp2(fmaf(s1[qi][r], C1, -mm[qi]));                   \
      }                                                                       \
      union { unsigned u[4]; bf16x8 v; } pk;                                  \
      pk.u[0] = cvt_pk_bf16(p[0], p[1]);                                      \
      pk.u[1] = cvt_pk_bf16(p[2], p[3]);                                      \
      pk.u[2] = cvt_pk_bf16(p[4], p[5]);                                      \
      pk.u[3] = cvt_pk_bf16(p[6], p[7]);                                      \
      _Pragma("unroll")                                                       \
      for (int df = 0; df < 4; ++df)                                          \
        oacc[qi][df] = MFMA_B16(pk.v, vv[df], oacc[qi][df], 0, 0, 0);         \
      oaccS[qi] = MFMA_B16(pk.v, onesv.v, oaccS[qi], 0, 0, 0);                \
    }                                                                         \
  }

__global__ __launch_bounds__(256)
void attn_kernel(const __hip_bfloat16* __restrict__ Qb,
                 const __hip_bfloat16* __restrict__ Kb,
                 const __hip_bfloat16* __restrict__ VTb,
                 __hip_bfloat16* __restrict__ vec) {
  __shared__ __align__(16) char lds0[8192];
  __shared__ __align__(16) char lds1[8192];
  const int t = threadIdx.x, w = t >> 6, l = t & 63;
  const int bid = blockIdx.x;
  const int slot = bid >> 3;
  const int bh = (bid & 7) * 4 + (slot & 3);
  const int qt = slot >> 2;                       // 0..15
  const int b = bh >> 4, h = bh & 15;
  const __hip_bfloat16* Q = Qb + (size_t)bh * S_SEQ * DH;
  const char* Kf = (const char*)Kb + (size_t)bh * 262144;
  const char* Vf = (const char*)VTb + (size_t)bh * 262144;
  const int ll = l & 15, lg = l >> 4;
  const int l16 = l * 16;
  const int woff = w * 1024 + l16;
  const int wl16 = woff;
  constexpr float C1   = 0.125f * 1.44269504088896f;
  constexpr float THR2 = 11.5416f;

  const int qbase = qt * 128 + w * 32;
  bf16x8 qf[2][2];
#pragma unroll
  for (int qi = 0; qi < 2; ++qi) {
    qf[qi][0] = *(const bf16x8*)(Q + (size_t)(qbase + qi * 16 + ll) * 64 + lg * 8);
    qf[qi][1] = *(const bf16x8*)(Q + (size_t)(qbase + qi * 16 + ll) * 64 + 32 + lg * 8);
  }

  union { unsigned u[4]; bf16x8 v; } onesv;
  onesv.u[0] = 0x3F803F80u; onesv.u[1] = 0x3F803F80u;
  onesv.u[2] = 0x3F803F80u; onesv.u[3] = 0x3F803F80u;

  float mm[2] = {-1e30f, -1e30f};
  f32x4 oacc[2][4] = {};
  f32x4 oaccS[2] = {};

  STAGE(lds0, 0);

  for (int tile = 0; tile < 64; ++tile) {
    __syncthreads();
    const char* cur = (tile & 1) ? lds1 : lds0;
    char* nxt       = (tile & 1) ? lds0 : lds1;
    if (tile < 63) STAGE(nxt, (tile + 1) * 4096);
    bf16x8 kk[4], vv[4];
#pragma unroll
    for (int i = 0; i < 4; ++i) {
      kk[i] = *(const bf16x8*)(cur + i * 1024 + l16);
      vv[i] = *(const bf16x8*)(cur + 4096 + i * 1024 + l16);
    }
    COMPUTE(kk, vv);
  }

#pragma unroll
  for (int qi = 0; qi < 2; ++qi) {
    float invR[4];
#pragma unroll
    for (int r = 0; r < 4; ++r) invR[r] = 1.0f / oaccS[qi][r];
#pragma unroll
    for (int df = 0; df < 4; ++df)
#pragma unroll
      for (int r = 0; r < 4; ++r) {
        const int row = qbase + qi * 16 + 4 * lg + r;
        const int e = h * 64 + df * 16 + ll;
        vec[((size_t)row * 2 + b) * 1024 + e] =
            __float2bfloat16(oacc[qi][df][r] * invR[r]);
      }
  }
}

// --------------------- residual add + LayerNorm (fused) ---------------------
__global__ __launch_bounds__(256)
void add_ln_kernel(const float* __restrict__ X, const float* __restrict__ Yadd,
                   const float* __restrict__ g, const float* __restrict__ bb,
                   float* __restrict__ out_f32,
                   __hip_bfloat16* __restrict__ out_b16) {
  const int row = blockIdx.x, t = threadIdx.x;
  const float4 x4 = *(const float4*)(X + (size_t)row * 1024 + t * 4);
  const float4 a4 = *(const float4*)(Yadd + (size_t)row * 1024 + t * 4);
  float v[4] = {x4.x + a4.x, x4.y + a4.y, x4.z + a4.z, x4.w + a4.w};
  float s = v[0] + v[1] + v[2] + v[3];
  float s2 = v[0] * v[0] + v[1] * v[1] + v[2] * v[2] + v[3] * v[3];
#pragma unroll
  for (int off = 1; off < 64; off <<= 1) {
    s += __shfl_xor(s, off);
    s2 += __shfl_xor(s2, off);
  }
  __shared__ float rs[4], rs2[4];
  if ((t & 63) == 0) { rs[t >> 6] = s; rs2[t >> 6] = s2; }
  __syncthreads();
  const float tot = rs[0] + rs[1] + rs[2] + rs[3];
  const float tot2 = rs2[0] + rs2[1] + rs2[2] + rs2[3];
  const float mu = tot * (1.0f / 1024.0f);
  const float var = tot2 * (1.0f / 1024.0f) - mu * mu;
  const float rstd = rsqrtf(var + 1e-5f);
  const float4 g4 = *(const float4*)(g + t * 4);
  const float4 b4 = *(const float4*)(bb + t * 4);
  float y[4];
  y[0] = (v[0] - mu) * rstd * g4.x + b4.x;
  y[1] = (v[1] - mu) * rstd * g4.y + b4.y;
  y[2] = (v[2] - mu) * rstd * g4.z + b4.z;
  y[3] = (v[3] - mu) * rstd * g4.w + b4.w;
  *(float4*)(out_f32 + (size_t)row * 1024 + t * 4) =
      make_float4(y[0], y[1], y[2], y[3]);
  uint2 pk2;
  pk2.x = cvt_pk_bf16(y[0], y[1]);
  pk2.y = cvt_pk_bf16(y[2], y[3]);
  *(uint2*)(out_b16 + (size_t)row * 1024 + t * 4) = pk2;
}

// ---------------- residual add + LayerNorm + 2*y + pe (final) ---------------
__global__ __launch_bounds__(256)
void final_kernel(const float* __restrict__ X, const float* __restrict__ Yadd,
                  const float* __restrict__ g, const float* __restrict__ bb,
                  const float* __restrict__ pe, float* __restrict__ out) {
  const int row = blockIdx.x, t = threadIdx.x;
  const float4 x4 = *(const float4*)(X + (size_t)row * 1024 + t * 4);
  const float4 a4 = *(const float4*)(Yadd + (size_t)row * 1024 + t * 4);
  float v[4] = {x4.x + a4.x, x4.y + a4.y, x4.z + a4.z, x4.w + a4.w};
  float s = v[0] + v[1] + v[2] + v[3];
  float s2 = v[0] * v[0] + v[1] * v[1] + v[2] * v[2] + v[3] * v[3];
#pragma unroll
  for (int off = 1; off < 64; off <<= 1) {
    s += __shfl_xor(s, off);
    s2 += __shfl_xor(s2, off);
  }
  __shared__ float rs[4], rs2[4];
  if ((t & 63) == 0) { rs[t >> 6] = s; rs2[t >> 6] = s2; }
  __syncthreads();
  const float tot = rs[0] + rs[1] + rs[2] + rs[3];
  const float tot2 = rs2[0] + rs2[1] + rs2[2] + rs2[3];
  const float mu = tot * (1.0f / 1024.0f);
  const float var = tot2 * (1.0f / 1024.0f) - mu * mu;
  const float rstd = rsqrtf(var + 1e-5f);
  const float4 g4 = *(const float4*)(g + t * 4);
  const float4 b4 = *(const float4*)(bb + t * 4);
  const int bidx = row & 1;
  const float4 p4 = *(const float4*)(pe + bidx * 1024 + t * 4);
  float y[4];
  y[0] = 2.0f * ((v[0] - mu) * rstd * g4.x + b4.x) + p4.x;
  y[1] = 2.0f * ((v[1] - mu) * rstd * g4.y + b4.y) + p4.y;
  y[2] = 2.0f * ((v[2] - mu) * rstd * g4.z + b4.z) + p4.z;
  y[3] = 2.0f * ((v[3] - mu) * rstd * g4.w + b4.w) + p4.w;
  *(float4*)(out + (size_t)row * 1024 + t * 4) = make_float4(y[0], y[1], y[2], y[3]);
}

// ---------------------------------------------------------------------------
extern "C" void kernel_launch(void* const* d_in, const int* in_sizes, int n_in,
                              void* d_out, int out_size, void* d_ws,
                              size_t ws_size, hipStream_t stream) {
  const float* x   = (const float*)d_in[0];
  const float* Wq  = (const float*)d_in[1];
  const float* Wkv = (const float*)d_in[2];
  const float* Wo  = (const float*)d_in[3];
  const float* g1  = (const float*)d_in[4];
  const float* b1  = (const float*)d_in[5];
  const float* Wff = (const float*)d_in[6];
  const float* g2  = (const float*)d_in[7];
  const float* b2  = (const float*)d_in[8];

  char* ws = (char*)d_ws;
  __hip_bfloat16* Wqkv_b = (__hip_bfloat16*)(ws + 0);          // 6 MB
  __hip_bfloat16* Wo_b   = (__hip_bfloat16*)(ws + 6 * WS_MB);  // 2 MB
  __hip_bfloat16* Wff_b  = (__hip_bfloat16*)(ws + 8 * WS_MB);  // 2 MB
  __hip_bfloat16* Xb     = (__hip_bfloat16*)(ws + 10 * WS_MB); // 8 MB
  __hip_bfloat16* Qb     = (__hip_bfloat16*)(ws + 18 * WS_MB); // 8 MB
  __hip_bfloat16* Kb     = (__hip_bfloat16*)(ws + 26 * WS_MB); // 8 MB (frag layout)
  __hip_bfloat16* VTb    = (__hip_bfloat16*)(ws + 34 * WS_MB); // 8 MB (frag layout)
  __hip_bfloat16* vecb   = (__hip_bfloat16*)(ws + 42 * WS_MB); // 8 MB
  float* attn            = (float*)(ws + 18 * WS_MB);          // 16 MB (alias Q+K)
  float* out1            = (float*)(ws + 50 * WS_MB);          // 16 MB
  __hip_bfloat16* out1b  = (__hip_bfloat16*)(ws + 66 * WS_MB); // 8 MB
  float* ffb             = (float*)(ws + 34 * WS_MB);          // 16 MB (alias VT+vec)
  float* pe              = (float*)(ws + 74 * WS_MB);          // 8 KB

  prep_kernel<<<9217, 256, 0, stream>>>(x, Wq, Wkv, Wo, Wff, Xb, Wqkv_b,
                                        Wo_b, Wff_b, pe);
  gemm_bt<1, 128><<<dim3(24, 32), 256, 0, stream>>>(Xb, Wqkv_b, nullptr, Qb,
                                                    Kb, VTb, 3072, 1024);
  attn_kernel<<<dim3(512), 256, 0, stream>>>(Qb, Kb, VTb, vecb);
  gemm_bt<0, 64><<<dim3(16, 32), 256, 0, stream>>>(vecb, Wo_b, attn, nullptr,
                                                   nullptr, nullptr, 1024, 1024);
  add_ln_kernel<<<4096, 256, 0, stream>>>(x, attn, g1, b1, out1, out1b);
  gemm_bt<0, 64><<<dim3(16, 32), 256, 0, stream>>>(out1b, Wff_b, ffb, nullptr,
                                                   nullptr, nullptr, 1024, 1024);
  final_kernel<<<4096, 256, 0, stream>>>(out1, ffb, g2, b2, pe, (float*)d_out);
}